// Round 17
// baseline (1749.028 us; speedup 1.0000x reference)
//
#include <hip/hip_runtime.h>
#include <stdint.h>

typedef unsigned short u16;
typedef __attribute__((ext_vector_type(8))) short short8;
typedef __attribute__((ext_vector_type(4))) float f32x4;

__device__ __forceinline__ float bf2f(u16 u){
  union { unsigned int i; float f; } v; v.i = ((unsigned int)u) << 16; return v.f;
}
__device__ __forceinline__ u16 f2bf(float f){
  union { float f; unsigned int i; } v; v.f = f;
  return (u16)((v.i + 0x7fffu + ((v.i >> 16) & 1u)) >> 16);
}
__device__ __forceinline__ int imin(int a, int b){ return a < b ? a : b; }

__device__ __forceinline__ void gl_lds16(const void* g, void* l){
  __builtin_amdgcn_global_load_lds(
      (const __attribute__((address_space(1))) void*)g,
      (__attribute__((address_space(3))) void*)l, 16, 0, 0);
}

// ---------------- f32 -> bf16 conversion ----------------
__global__ __launch_bounds__(256) void conv_k(const float* __restrict__ src,
                                              u16* __restrict__ dst, long long n){
  long long i = (long long)blockIdx.x * 256 + threadIdx.x;
  long long st = (long long)gridDim.x * 256;
  for (; i < n; i += st) dst[i] = f2bf(src[i]);
}
__global__ __launch_bounds__(256) void fill_f32(float* __restrict__ p, float val){
  int i = blockIdx.x * 256 + threadIdx.x;
  if (i < 32768) p[i] = val;
}
__global__ __launch_bounds__(256) void copyf32_k(const uint4* __restrict__ s, uint4* __restrict__ d){
  size_t i = (size_t)blockIdx.x * blockDim.x + threadIdx.x;
  d[i] = s[i];
}

// ---------------- f32 transpose of ain_w K-slice: out[c][d]=W[512+d][c] ----------------
__global__ __launch_bounds__(256) void transp_f32(const float* __restrict__ w,
                                                  float* __restrict__ o){
  __shared__ float sh[64][65];
  int bd = blockIdx.x & 7, bc = blockIdx.x >> 3;
  int t = threadIdx.x;
  int lane = t & 63, r4 = t >> 6;
  #pragma unroll
  for (int r = 0; r < 64; r += 4){
    int dd = r + r4, cc = lane;
    sh[dd][cc] = w[(size_t)(512 + bd * 64 + dd) * 512 + bc * 64 + cc];
  }
  __syncthreads();
  #pragma unroll
  for (int r = 0; r < 64; r += 4){
    int cc = r + r4, dd = lane;
    o[(size_t)(bc * 64 + cc) * 512 + bd * 64 + dd] = sh[dd][cc];
  }
}

// ---------------- block reduce ----------------
__device__ __forceinline__ float block_sum(float v, float* sh){
  #pragma unroll
  for (int o = 32; o; o >>= 1) v += __shfl_down(v, o, 64);
  int wv = threadIdx.x >> 6, ln = threadIdx.x & 63;
  __syncthreads();
  if (ln == 0) sh[wv] = v;
  __syncthreads();
  float r = 0.f;
  for (int i = 0; i < 4; ++i) r += sh[i];
  return r;
}
__device__ __forceinline__ float block_maxr(float v, float* sh){
  #pragma unroll
  for (int o = 32; o; o >>= 1) v = fmaxf(v, __shfl_down(v, o, 64));
  int wv = threadIdx.x >> 6, ln = threadIdx.x & 63;
  __syncthreads();
  if (ln == 0) sh[wv] = v;
  __syncthreads();
  float r = sh[0];
  for (int i = 1; i < 4; ++i) r = fmaxf(r, sh[i]);
  return r;
}

// ---------------- f32 GEMM 128x128 tile (8x8/thread, BK=8) — best occupancy ----------------
// wt=1: B' = W^T, W [N][K]; wt=0: B' = B, B [K][N].
__global__ __launch_bounds__(256) void gemm_f32(
    const float* __restrict__ A, const float* __restrict__ W, float* __restrict__ C,
    int M, int N, int K, int lda, int ldw, int ldc,
    long long sAo, long long sAi, int inner,
    long long sWo, long long sWi,
    long long sCo, long long sCi,
    const float* __restrict__ bias, int bis,
    const float* __restrict__ rscale, int rs_shift,
    const int* __restrict__ gather, int wt, int ntiles)
{
  __shared__ float As[8][132];
  __shared__ float Bs[8][132];
  int bz = blockIdx.y;
  int oz = bz / inner, iz = bz - oz * inner;
  const float* Ab = A + (size_t)oz * sAo + (size_t)iz * sAi;
  const float* Wb = W + (size_t)oz * sWo + (size_t)iz * sWi;
  float* Cb = C + (size_t)oz * sCo + (size_t)iz * sCi;
  const float* bp = bias ? bias + (size_t)iz * bis : nullptr;

  int mt = blockIdx.x / ntiles, nt = blockIdx.x - mt * ntiles;
  int t = threadIdx.x;
  int tr = t >> 4, tc = t & 15;

  float acc[8][8];
  #pragma unroll
  for (int i = 0; i < 8; ++i)
    #pragma unroll
    for (int j = 0; j < 8; ++j) acc[i][j] = 0.f;

  int arow = t >> 1, akq = (t & 1) * 4;
  int ra = imin(mt * 128 + arow, M - 1);
  if (gather) ra = gather[ra];
  const float* pA = Ab + (size_t)ra * lda + akq;
  int brow = t >> 1, bkq = (t & 1) * 4;
  int rb = imin(nt * 128 + brow, N - 1);
  const float* pB1 = Wb + (size_t)rb * ldw + bkq;
  int bkk = t >> 5, bcol = (t & 31) * 4;
  const float* pB0 = Wb + (size_t)bkk * ldw + nt * 128 + bcol;

  for (int kt = 0; kt < K; kt += 8){
    f32x4 a4 = *(const f32x4*)(pA + kt);
    #pragma unroll
    for (int z = 0; z < 4; ++z) As[akq + z][arow] = a4[z];
    if (wt){
      f32x4 b4 = *(const f32x4*)(pB1 + kt);
      #pragma unroll
      for (int z = 0; z < 4; ++z) Bs[bkq + z][brow] = b4[z];
    } else {
      f32x4 b4 = *(const f32x4*)(pB0 + (size_t)kt * ldw);
      #pragma unroll
      for (int z = 0; z < 4; ++z) Bs[bkk][bcol + z] = b4[z];
    }
    __syncthreads();
    #pragma unroll
    for (int kk = 0; kk < 8; ++kk){
      f32x4 a0 = *(const f32x4*)&As[kk][tr * 8];
      f32x4 a1 = *(const f32x4*)&As[kk][tr * 8 + 4];
      f32x4 b0 = *(const f32x4*)&Bs[kk][tc * 8];
      f32x4 b1 = *(const f32x4*)&Bs[kk][tc * 8 + 4];
      #pragma unroll
      for (int i = 0; i < 4; ++i){
        #pragma unroll
        for (int j = 0; j < 4; ++j){
          acc[i][j]         += a0[i] * b0[j];
          acc[i][j + 4]     += a0[i] * b1[j];
          acc[i + 4][j]     += a1[i] * b0[j];
          acc[i + 4][j + 4] += a1[i] * b1[j];
        }
      }
    }
    __syncthreads();
  }

  #pragma unroll
  for (int i = 0; i < 8; ++i){
    int row = mt * 128 + tr * 8 + i;
    if (row >= M) continue;
    float rs = rscale ? rscale[row >> rs_shift] : 1.f;
    #pragma unroll
    for (int j = 0; j < 8; ++j){
      int col = nt * 128 + tc * 8 + j;
      float v = acc[i][j];
      if (bp) v += bp[col];
      Cb[(size_t)row * ldc + col] = v * rs;
    }
  }
}

// ---------------- f32 GEMM 128x64 tile (8x4/thread, BK=16) ----------------
__global__ __launch_bounds__(256) void gemm_f32b(
    const float* __restrict__ A, const float* __restrict__ W, float* __restrict__ C,
    int M, int N, int K, int lda, int ldw, int ldc,
    long long sAo, long long sAi, int inner,
    long long sWo, long long sWi,
    long long sCo, long long sCi,
    const float* __restrict__ bias, int bis,
    const float* __restrict__ rscale, int rs_shift,
    const int* __restrict__ gather, int wt, int ntiles)
{
  __shared__ float As[16][132];
  __shared__ float Bs[16][68];
  int bz = blockIdx.y;
  int oz = bz / inner, iz = bz - oz * inner;
  const float* Ab = A + (size_t)oz * sAo + (size_t)iz * sAi;
  const float* Wb = W + (size_t)oz * sWo + (size_t)iz * sWi;
  float* Cb = C + (size_t)oz * sCo + (size_t)iz * sCi;
  const float* bp = bias ? bias + (size_t)iz * bis : nullptr;

  int mt = blockIdx.x / ntiles, nt = blockIdx.x - mt * ntiles;
  int t = threadIdx.x;
  int tr = t >> 4, tc = t & 15;

  float acc[8][4];
  #pragma unroll
  for (int i = 0; i < 8; ++i)
    #pragma unroll
    for (int j = 0; j < 4; ++j) acc[i][j] = 0.f;

  int arow = t >> 1, akq = (t & 1) * 8;
  int ra = imin(mt * 128 + arow, M - 1);
  if (gather) ra = gather[ra];
  const float* pA = Ab + (size_t)ra * lda + akq;
  int brow = t >> 2, bkq = (t & 3) * 4;
  int rb = imin(nt * 64 + brow, N - 1);
  const float* pB1 = Wb + (size_t)rb * ldw + bkq;
  int bkk = t >> 4, bcol = (t & 15) * 4;
  const float* pB0 = Wb + (size_t)bkk * ldw + nt * 64 + bcol;

  for (int kt = 0; kt < K; kt += 16){
    f32x4 a4 = *(const f32x4*)(pA + kt);
    f32x4 a4b = *(const f32x4*)(pA + kt + 4);
    #pragma unroll
    for (int z = 0; z < 4; ++z){ As[akq + z][arow] = a4[z]; As[akq + 4 + z][arow] = a4b[z]; }
    if (wt){
      f32x4 b4 = *(const f32x4*)(pB1 + kt);
      #pragma unroll
      for (int z = 0; z < 4; ++z) Bs[bkq + z][brow] = b4[z];
    } else {
      f32x4 b4 = *(const f32x4*)(pB0 + (size_t)kt * ldw);
      #pragma unroll
      for (int z = 0; z < 4; ++z) Bs[bkk][bcol + z] = b4[z];
    }
    __syncthreads();
    #pragma unroll
    for (int kk = 0; kk < 16; ++kk){
      f32x4 a0 = *(const f32x4*)&As[kk][tr * 8];
      f32x4 a1 = *(const f32x4*)&As[kk][tr * 8 + 4];
      f32x4 b0 = *(const f32x4*)&Bs[kk][tc * 4];
      #pragma unroll
      for (int i = 0; i < 4; ++i){
        #pragma unroll
        for (int j = 0; j < 4; ++j){
          acc[i][j]     += a0[i] * b0[j];
          acc[i + 4][j] += a1[i] * b0[j];
        }
      }
    }
    __syncthreads();
  }

  #pragma unroll
  for (int i = 0; i < 8; ++i){
    int row = mt * 128 + tr * 8 + i;
    if (row >= M) continue;
    float rs = rscale ? rscale[row >> rs_shift] : 1.f;
    #pragma unroll
    for (int j = 0; j < 4; ++j){
      int col = nt * 64 + tc * 4 + j;
      float v = acc[i][j];
      if (bp) v += bp[col];
      Cb[(size_t)row * ldc + col] = v * rs;
    }
  }
}

// ---------------- LayerNorm f32 -> kvf slot rows ----------------
__global__ __launch_bounds__(256) void ln_f32(
    const float* __restrict__ state, const float* __restrict__ g,
    const float* __restrict__ be, float* __restrict__ kvf)
{
  int row = blockIdx.x;
  int b = row >> 7, s = row & 127;
  const float* xp = state + (size_t)row * 512;
  int t = threadIdx.x;
  float x0 = xp[t], x1 = xp[t + 256];
  __shared__ float sh[4];
  float sx  = block_sum(x0 + x1, sh);
  float sxx = block_sum(x0 * x0 + x1 * x1, sh);
  float mu = sx * (1.f / 512.f);
  float var = fmaxf(sxx * (1.f / 512.f) - mu * mu, 0.f);
  float rstd = rsqrtf(var + 1e-5f);
  float* o = kvf + (size_t)b * 327680 + (size_t)(512 + s) * 512;
  o[t]       = (x0 - mu) * rstd * g[t]       + be[t];
  o[t + 256] = (x1 - mu) * rstd * g[t + 256] + be[t + 256];
}

// ---------------- f32 softmax, in-place, 640 cols, with scale ----------------
__global__ __launch_bounds__(256) void softmax_f32(float* __restrict__ sc, float scale)
{
  size_t row = blockIdx.x;
  float* sp = sc + row * 640;
  int t = threadIdx.x;
  float v0 = sp[t], v1 = sp[t + 256];
  float v2 = (t < 128) ? sp[t + 512] : -3.0e38f;
  __shared__ float sh[4];
  float m = block_maxr(fmaxf(fmaxf(v0, v1), v2), sh);
  float e0 = expf((v0 - m) * scale), e1 = expf((v1 - m) * scale);
  float e2 = (t < 128) ? expf((v2 - m) * scale) : 0.f;
  float ssum = block_sum(e0 + e1 + e2, sh);
  float inv = 1.f / ssum;
  sp[t] = e0 * inv;
  sp[t + 256] = e1 * inv;
  if (t < 128) sp[t + 512] = e2 * inv;
}

// ---------------- read-gate scores (exact f32) ----------------
__global__ __launch_bounds__(64) void rscore_k(
    const float* __restrict__ state, const float* __restrict__ rw,
    const float* __restrict__ rb, float* __restrict__ rsc)
{
  int row = blockIdx.x, l = threadIdx.x;
  const float* sp = state + (size_t)row * 512;
  float a = 0.f;
  for (int d = l; d < 512; d += 64) a += sp[d] * rw[d];
  #pragma unroll
  for (int o = 32; o; o >>= 1) a += __shfl_down(a, o, 64);
  if (l == 0) rsc[row] = a + rb[0];
}

// ---------------- top-8 read indices ----------------
__global__ void topk_read(const float* __restrict__ sc, float* __restrict__ out_idx)
{
  int b = threadIdx.x; if (b >= 64) return;
  const float* p = sc + b * 128;
  unsigned long long u0 = 0, u1 = 0;
  for (int it = 0; it < 8; ++it){
    float best = -3.0e38f; int bi = 0;
    for (int j = 0; j < 128; ++j){
      bool used = (j < 64) ? ((u0 >> j) & 1) : ((u1 >> (j - 64)) & 1);
      float v = p[j];
      if (!used && v > best){ best = v; bi = j; }
    }
    if (bi < 64) u0 |= 1ull << bi; else u1 |= 1ull << (bi - 64);
    out_idx[b * 8 + it] = (float)bi;
  }
}

// ---------------- gate f32 ----------------
__global__ __launch_bounds__(256) void gate_f32(
    const float* __restrict__ aout, const float* __restrict__ gw, const float* __restrict__ gb,
    float* __restrict__ out_eidx, float* __restrict__ out_ew, float* __restrict__ gscale)
{
  int b = blockIdx.x, t = threadIdx.x;
  __shared__ float mean[512];
  __shared__ float lg[64];
  const float* ap = aout + (size_t)b * 65536;
  float s0 = 0.f, s1 = 0.f;
  for (int s = 0; s < 128; ++s){
    s0 += ap[s * 512 + t];
    s1 += ap[s * 512 + t + 256];
  }
  mean[t] = s0 * (1.f / 128.f);
  mean[t + 256] = s1 * (1.f / 128.f);
  __syncthreads();
  if (t < 64){
    float acc = gb[t];
    const float* gwr = gw + t * 512;
    for (int d = 0; d < 512; ++d) acc += mean[d] * gwr[d];
    lg[t] = acc;
  }
  __syncthreads();
  if (t == 0){
    int i0 = 0; float v0 = lg[0];
    for (int e = 1; e < 64; ++e) if (lg[e] > v0){ v0 = lg[e]; i0 = e; }
    int i1 = (i0 == 0) ? 1 : 0; float v1 = lg[i1];
    for (int e = 0; e < 64; ++e) if (e != i0 && lg[e] > v1){ v1 = lg[e]; i1 = e; }
    float e1 = expf(v1 - v0);
    float w0 = 1.f / (1.f + e1), w1 = e1 / (1.f + e1);
    out_eidx[b * 2]     = (float)i0;
    out_eidx[b * 2 + 1] = (float)i1;
    out_ew[b * 2]     = w0;
    out_ew[b * 2 + 1] = w1;
    gscale[b] = w0 + w1;
  }
}

// ---------------- slot-gate scores f32 ----------------
__global__ void slot_scores_f32(
    const float* __restrict__ eout, const float* __restrict__ sgw,
    const float* __restrict__ sgb, float* __restrict__ ssc)
{
  int row = blockIdx.x, l = threadIdx.x;
  const float* ep = eout + (size_t)row * 512;
  float a = 0.f;
  for (int d = l; d < 512; d += 64) a += ep[d] * sgw[d];
  #pragma unroll
  for (int o = 32; o; o >>= 1) a += __shfl_down(a, o, 64);
  if (l == 0) ssc[row] = a + sgb[0];
}

// ---------------- top-8 slots ----------------
__global__ void topk_slot(const float* __restrict__ sc, float* __restrict__ out_idx,
                          float* __restrict__ out_w, int* __restrict__ rowmap,
                          float* __restrict__ slotw_f)
{
  int b = threadIdx.x; if (b >= 64) return;
  const float* p = sc + b * 128;
  unsigned long long u0 = 0, u1 = 0;
  float vals[8]; int idx[8];
  for (int it = 0; it < 8; ++it){
    float best = -3.0e38f; int bi = 0;
    for (int j = 0; j < 128; ++j){
      bool used = (j < 64) ? ((u0 >> j) & 1) : ((u1 >> (j - 64)) & 1);
      float v = p[j];
      if (!used && v > best){ best = v; bi = j; }
    }
    if (bi < 64) u0 |= 1ull << bi; else u1 |= 1ull << (bi - 64);
    vals[it] = best; idx[it] = bi;
  }
  float m = vals[0], s = 0.f, e[8];
  for (int i = 0; i < 8; ++i){ e[i] = expf(vals[i] - m); s += e[i]; }
  float inv = 1.f / s;
  for (int i = 0; i < 8; ++i){
    float w = e[i] * inv;
    out_idx[b * 8 + i] = (float)idx[i];
    out_w[b * 8 + i]   = w;
    rowmap[b * 8 + i]  = b * 128 + idx[i];
    slotw_f[b * 8 + i] = w;
  }
}

// ---------------- scatter: f32 ns output + bf16 ns ----------------
__global__ __launch_bounds__(256) void finalize2_k(
    const float* __restrict__ upd, const int* __restrict__ rowmap,
    const float* __restrict__ slotw, const float* __restrict__ raw_state,
    float* __restrict__ nsf, u16* __restrict__ nsb)
{
  int m = blockIdx.x, t = threadIdx.x;
  int row = rowmap[m];
  float w = slotw[m];
  #pragma unroll
  for (int d = t; d < 512; d += 256){
    float st = raw_state[(size_t)row * 512 + d];
    float v = 0.7f * st + 0.3f * w * tanhf(upd[(size_t)m * 512 + d]);
    nsf[(size_t)row * 512 + d] = v;
    nsb[(size_t)row * 512 + d] = f2bf(v);
  }
}

// ---------------- bf16 MFMA GEMM (final output; verified) ----------------
__global__ __launch_bounds__(256) void gemm_bt(
    const u16* __restrict__ A, const u16* __restrict__ W, void* __restrict__ C,
    int M, int N, int K, int lda, int ldw, int ldc,
    long long sAo, long long sAi, int inner,
    long long sWo, long long sWi,
    long long sCo, long long sCi,
    const u16* __restrict__ bias, int bias_row,
    const float* __restrict__ rscale, int rs_shift,
    const int* __restrict__ gather,
    float oscale, int cf32, int ntiles)
{
  __shared__ __align__(16) u16 lA[128 * 32];
  __shared__ __align__(16) u16 lB[128 * 32];

  int bz = blockIdx.y;
  int oz = bz / inner, iz = bz - oz * inner;
  const u16* Ab = A + (size_t)oz * sAo + (size_t)iz * sAi;
  const u16* Wb = W + (size_t)oz * sWo + (size_t)iz * sWi;
  char* Cb = (char*)C + ((size_t)oz * sCo + (size_t)iz * sCi) * (cf32 ? 4 : 2);

  int mt = blockIdx.x / ntiles, nt = blockIdx.x - mt * ntiles;

  int tid = threadIdx.x;
  int wave = tid >> 6, lane = tid & 63;
  int wm = (wave >> 1) * 64, wn = (wave & 1) * 64;
  int fr = lane & 15, fq = lane >> 4;

  int m0  = tid >> 2, kc = tid & 3;
  int rA0 = imin(mt * 128 + m0,      M - 1);
  int rA1 = imin(mt * 128 + m0 + 64, M - 1);
  if (gather){ rA0 = gather[rA0]; rA1 = gather[rA1]; }
  int rB0 = imin(nt * 128 + m0,      N - 1);
  int rB1 = imin(nt * 128 + m0 + 64, N - 1);
  const u16* pA0 = Ab + (size_t)rA0 * lda + kc * 8;
  const u16* pA1 = Ab + (size_t)rA1 * lda + kc * 8;
  const u16* pB0 = Wb + (size_t)rB0 * ldw + kc * 8;
  const u16* pB1 = Wb + (size_t)rB1 * ldw + kc * 8;
  char* dA0 = (char*)lA + wave * 1024;
  char* dA1 = (char*)lA + 4096 + wave * 1024;
  char* dB0 = (char*)lB + wave * 1024;
  char* dB1 = (char*)lB + 4096 + wave * 1024;

  f32x4 zero = {0.f, 0.f, 0.f, 0.f};
  f32x4 acc[4][4];
  #pragma unroll
  for (int i = 0; i < 4; ++i)
    #pragma unroll
    for (int j = 0; j < 4; ++j) acc[i][j] = zero;

  for (int kt = 0; kt < K; kt += 32){
    gl_lds16(pA0 + kt, dA0);
    gl_lds16(pA1 + kt, dA1);
    gl_lds16(pB0 + kt, dB0);
    gl_lds16(pB1 + kt, dB1);
    __syncthreads();

    short8 afr[4], bfr[4];
    #pragma unroll
    for (int i = 0; i < 4; ++i){
      afr[i] = *(const short8*)&lA[(wm + i * 16 + fr) * 32 + fq * 8];
      bfr[i] = *(const short8*)&lB[(wn + i * 16 + fr) * 32 + fq * 8];
    }
    #pragma unroll
    for (int i = 0; i < 4; ++i)
      #pragma unroll
      for (int j = 0; j < 4; ++j)
        acc[i][j] = __builtin_amdgcn_mfma_f32_16x16x32_bf16(afr[i], bfr[j], acc[i][j], 0, 0, 0);
    __syncthreads();
  }

  #pragma unroll
  for (int i = 0; i < 4; ++i){
    #pragma unroll
    for (int j = 0; j < 4; ++j){
      #pragma unroll
      for (int r = 0; r < 4; ++r){
        int row = mt * 128 + wm + i * 16 + fq * 4 + r;
        int col = nt * 128 + wn + j * 16 + fr;
        if (row < M){
          float v = acc[i][j][r] * oscale;
          if (bias)   v += bf2f(bias[bias_row ? row : col]);
          if (rscale) v *= rscale[row >> rs_shift];
          size_t idx = (size_t)row * ldc + col;
          if (cf32) ((float*)Cb)[idx] = v;
          else      ((u16*)Cb)[idx]   = f2bf(v);
        }
      }
    }
  }
}

// ---------------- final out reduce ----------------
__global__ __launch_bounds__(256) void out_reduce(
    const float* __restrict__ part, const float* __restrict__ ob, float* __restrict__ out)
{
  int i = blockIdx.x * 256 + threadIdx.x;
  float a = ob[i & 511];
  for (int ks = 0; ks < 64; ++ks) a += part[(size_t)ks * 32768 + i];
  out[i] = a;
}

// ---------------- host helpers ----------------
static inline int hmin(int a, int b){ return a < b ? a : b; }

static inline void gemmF(hipStream_t st, const float* A, const float* W, float* C,
    int M, int N, int K, int lda, int ldw, int ldc,
    long long sAo, long long sAi, int inner,
    long long sWo, long long sWi, long long sCo, long long sCi, int batch,
    const float* bias, int bis, const float* rs, int rss, const int* gth, int wt)
{
  int mt = (M + 127) / 128, nt = (N + 127) / 128;
  gemm_f32<<<dim3(mt * nt, batch), dim3(256), 0, st>>>(
      A, W, C, M, N, K, lda, ldw, ldc, sAo, sAi, inner, sWo, sWi, sCo, sCi,
      bias, bis, rs, rss, gth, wt, nt);
}
static inline void gemmFb(hipStream_t st, const float* A, const float* W, float* C,
    int M, int N, int K, int lda, int ldw, int ldc,
    long long sAo, long long sAi, int inner,
    long long sWo, long long sWi, long long sCo, long long sCi, int batch,
    const float* bias, int bis, const float* rs, int rss, const int* gth, int wt)
{
  int mt = (M + 127) / 128, nt = (N + 63) / 64;
  gemm_f32b<<<dim3(mt * nt, batch), dim3(256), 0, st>>>(
      A, W, C, M, N, K, lda, ldw, ldc, sAo, sAi, inner, sWo, sWi, sCo, sCi,
      bias, bis, rs, rss, gth, wt, nt);
}
static inline void conv(hipStream_t st, const void* src, u16* dst, long long n){
  int blocks = hmin((int)((n + 255) / 256), 4096);
  conv_k<<<dim3(blocks), dim3(256), 0, st>>>((const float*)src, dst, n);
}

extern "C" void kernel_launch(void* const* d_in, const int* in_sizes, int n_in,
                              void* d_out, int out_size, void* d_ws, size_t ws_size,
                              hipStream_t stream)
{
  float* fo = (float*)d_out;

  static const int expect_sizes[22] = {
    16777216, 4194304, 262144, 512, 512, 512, 786432, 1536, 262144, 512,
    262144, 512, 32768, 64, 512, 1, 512, 1, 262144, 512, 33554432, 512 };
  bool ok = (n_in == 22);
  if (ok) for (int i = 0; i < 22; ++i) if (in_sizes[i] != expect_sizes[i]) ok = false;
  if (!ok){ fill_f32<<<dim3(128), dim3(256), 0, stream>>>(fo, 29.f * 1024.f); return; }
  if (out_size != 4228864){ fill_f32<<<dim3(128), dim3(256), 0, stream>>>(fo, 30.f * 1024.f); return; }

  const float* xR     = (const float*)d_in[0];
  const float* stateR = (const float*)d_in[1];
  const float* inwR   = (const float*)d_in[2];
  const float* inbR   = (const float*)d_in[3];
  const float* lngR   = (const float*)d_in[4];
  const float* lnbR   = (const float*)d_in[5];
  const float* ainwR  = (const float*)d_in[6];
  const float* ainbR  = (const float*)d_in[7];
  const float* aowR   = (const float*)d_in[8];
  const float* aobR   = (const float*)d_in[9];
  const float* expwR  = (const float*)d_in[10];
  const float* expbR  = (const float*)d_in[11];
  const float* gwR    = (const float*)d_in[12];
  const float* gbR    = (const float*)d_in[13];
  const float* rwR    = (const float*)d_in[14];
  const float* rbR    = (const float*)d_in[15];
  const float* sgwR   = (const float*)d_in[16];
  const float* sgbR   = (const float*)d_in[17];
  const float* stwR   = (const float*)d_in[18];
  const float* stbR   = (const float*)d_in[19];
  const float* outwR  = (const float*)d_in[20];
  const float* outbR  = (const float*)d_in[21];

  float* outp  = fo;
  float* nsf   = fo + 32768;
  float* sidx  = fo + 4227072;
  float* ridx  = fo + 4227584;
  float* eidx  = fo + 4228096;
  float* swout = fo + 4228224;
  float* ewout = fo + 4228736;

  char* wsp = (char*)d_ws;
  size_t o = 0;
  auto alloc = [&](size_t bytes){ size_t r = o; o += (bytes + 255) & ~(size_t)255; return r; };
  float* kvf    = (float*)(wsp + alloc(83886080));
  float* qf     = (float*)(wsp + alloc(16777216));
  float* qkpv   = (float*)(wsp + alloc(16777216));
  float* scoresb= (float*)(wsp + alloc(20971520));
  float* attnf  = (float*)(wsp + alloc(16777216));
  float* opart  = (float*)(wsp + alloc(8388608));
  float* updf   = (float*)(wsp + alloc(1048576));
  float* ainwT  = (float*)(wsp + alloc(1048576));
  float* rsc    = (float*)(wsp + alloc(32768));
  float* ssc    = (float*)(wsp + alloc(32768));
  float* gscale = (float*)(wsp + alloc(256));
  int*   rowmap = (int*)  (wsp + alloc(2048));
  float* slotw  = (float*)(wsp + alloc(2048));
  u16* nsb      = (u16*)  (wsp + alloc(8388608));

  u16*   out_w_c = (u16*)kvf;
  float* aoutf   = qf;
  float* eoutf   = attnf;

  if (ws_size < o){ fill_f32<<<dim3(128), dim3(256), 0, stream>>>(fo, 31.f * 1024.f); return; }

  transp_f32<<<dim3(64), dim3(256), 0, stream>>>(ainwR, ainwT);
  conv(stream, stateR, nsb, 4194304);

  // 1) LayerNorm -> kvf slots ; read-gate
  ln_f32<<<dim3(8192), dim3(256), 0, stream>>>(stateR, lngR, lnbR, kvf);
  rscore_k<<<dim3(8192), dim3(64), 0, stream>>>(stateR, rwR, rbR, rsc);
  topk_read<<<dim3(1), dim3(64), 0, stream>>>(rsc, ridx);
  // 2) x_proj -> kvf rows 0..511
  gemmF(stream, xR, inwR, kvf, 512, 512, 512, 512, 512, 512,
        262144, 0, 1, 0, 0, 327680, 0, 64, inbR, 0, nullptr, 0, nullptr, 1);
  // 3) q -> qf
  gemmFb(stream, kvf + 262144, ainwR, qf, 128, 512, 512, 512, 512, 512,
        327680, 0, 1, 0, 0, 65536, 0, 64, ainbR, 0, nullptr, 0, nullptr, 1);
  // 4) attention (GEMM factorization), chunks of 16 batches
  for (int cb = 0; cb < 4; ++cb){
    const float* qc  = qf  + (size_t)cb * 16 * 65536;
    const float* kvc = kvf + (size_t)cb * 16 * 327680;
    float* atc = attnf + (size_t)cb * 16 * 65536;
    gemmFb(stream, qc, ainwT, qkpv, 128, 512, 128, 512, 512, 512,
          65536, 128, 4, 0, 128, 262144, 65536, 64,
          nullptr, 0, nullptr, 0, nullptr, 1);
    gemmFb(stream, qkpv, kvc, scoresb, 128, 640, 512, 512, 512, 640,
          262144, 65536, 4, 327680, 0, 327680, 81920, 64,
          nullptr, 0, nullptr, 0, nullptr, 1);
    softmax_f32<<<dim3(8192), dim3(256), 0, stream>>>(scoresb, 0.08838834764831845f);
    gemmFb(stream, scoresb, kvc, qkpv, 128, 512, 640, 640, 512, 512,
          327680, 81920, 4, 327680, 0, 262144, 65536, 64,
          nullptr, 0, nullptr, 0, nullptr, 0);
    gemmFb(stream, qkpv, ainwR + (size_t)1024 * 512, atc, 128, 128, 512, 512, 512, 512,
          262144, 65536, 4, 0, 65536, 65536, 128, 64,
          ainbR + 1024, 128, nullptr, 0, nullptr, 1);
  }
  // 5) attn_out
  gemmF(stream, attnf, aowR, aoutf, 8192, 512, 512, 512, 512, 512,
        0, 0, 1, 0, 0, 0, 0, 1, aobR, 0, nullptr, 0, nullptr, 1);
  // 6) gate
  gate_f32<<<dim3(64), dim3(256), 0, stream>>>(aoutf, gwR, gbR, eidx, ewout, gscale);
  // 7) expert_out
  gemmF(stream, aoutf, expwR, eoutf, 8192, 512, 512, 512, 512, 512,
        0, 0, 1, 0, 0, 0, 0, 1, expbR, 0, gscale, 7, nullptr, 1);
  // 8) slot scores + top-8
  slot_scores_f32<<<dim3(8192), dim3(64), 0, stream>>>(eoutf, sgwR, sgbR, ssc);
  topk_slot<<<dim3(1), dim3(64), 0, stream>>>(ssc, sidx, swout, rowmap, slotw);
  // 9) upd
  gemmFb(stream, eoutf, stwR, updf, 512, 512, 512, 512, 512, 512,
        0, 0, 1, 0, 0, 0, 0, 1, stbR, 0, nullptr, 0, rowmap, 1);
  // 10) next_state
  copyf32_k<<<dim3(4096), dim3(256), 0, stream>>>((const uint4*)stateR, (uint4*)nsf);
  finalize2_k<<<dim3(512), dim3(256), 0, stream>>>(updf, rowmap, slotw, stateR, nsf, nsb);
  // 11) out_w -> bf16 (overlays kvf)
  conv(stream, outwR, out_w_c, 33554432);
  // 12) final output GEMM (bf16 MFMA) + reduce
  gemm_bt<<<dim3(4, 64), dim3(256), 0, stream>>>(
      nsb, out_w_c, opart, 64, 512, 1024, 65536, 65536, 512,
      1024, 0, 1, 1024, 0, 32768, 0,
      nullptr, 0, nullptr, 0, nullptr, 1.f, 1, 4);
  out_reduce<<<dim3(128), dim3(256), 0, stream>>>(opart, outbR, outp);
}

// Round 18
// 1609.658 us; speedup vs baseline: 1.0866x; 1.0866x over previous
//
#include <hip/hip_runtime.h>
#include <stdint.h>

typedef unsigned short u16;
typedef __attribute__((ext_vector_type(8))) short short8;
typedef __attribute__((ext_vector_type(4))) float f32x4;

__device__ __forceinline__ float bf2f(u16 u){
  union { unsigned int i; float f; } v; v.i = ((unsigned int)u) << 16; return v.f;
}
__device__ __forceinline__ u16 f2bf(float f){
  union { float f; unsigned int i; } v; v.f = f;
  return (u16)((v.i + 0x7fffu + ((v.i >> 16) & 1u)) >> 16);
}
__device__ __forceinline__ int imin(int a, int b){ return a < b ? a : b; }

__device__ __forceinline__ void gl_lds16(const void* g, void* l){
  __builtin_amdgcn_global_load_lds(
      (const __attribute__((address_space(1))) void*)g,
      (__attribute__((address_space(3))) void*)l, 16, 0, 0);
}

// ---------------- f32 -> bf16 conversion ----------------
__global__ __launch_bounds__(256) void conv_k(const float* __restrict__ src,
                                              u16* __restrict__ dst, long long n){
  long long i = (long long)blockIdx.x * 256 + threadIdx.x;
  long long st = (long long)gridDim.x * 256;
  for (; i < n; i += st) dst[i] = f2bf(src[i]);
}
__global__ __launch_bounds__(256) void fill_f32(float* __restrict__ p, float val){
  int i = blockIdx.x * 256 + threadIdx.x;
  if (i < 32768) p[i] = val;
}
__global__ __launch_bounds__(256) void copyf32_k(const uint4* __restrict__ s, uint4* __restrict__ d){
  size_t i = (size_t)blockIdx.x * blockDim.x + threadIdx.x;
  d[i] = s[i];
}

// ---------------- f32 transpose of ain_w K-slice ----------------
__global__ __launch_bounds__(256) void transp_f32(const float* __restrict__ w,
                                                  float* __restrict__ o){
  __shared__ float sh[64][65];
  int bd = blockIdx.x & 7, bc = blockIdx.x >> 3;
  int t = threadIdx.x;
  int lane = t & 63, r4 = t >> 6;
  #pragma unroll
  for (int r = 0; r < 64; r += 4){
    int dd = r + r4, cc = lane;
    sh[dd][cc] = w[(size_t)(512 + bd * 64 + dd) * 512 + bc * 64 + cc];
  }
  __syncthreads();
  #pragma unroll
  for (int r = 0; r < 64; r += 4){
    int cc = r + r4, dd = lane;
    o[(size_t)(bc * 64 + cc) * 512 + bd * 64 + dd] = sh[dd][cc];
  }
}

// ---------------- block reduce ----------------
__device__ __forceinline__ float block_sum(float v, float* sh){
  #pragma unroll
  for (int o = 32; o; o >>= 1) v += __shfl_down(v, o, 64);
  int wv = threadIdx.x >> 6, ln = threadIdx.x & 63;
  __syncthreads();
  if (ln == 0) sh[wv] = v;
  __syncthreads();
  float r = 0.f;
  for (int i = 0; i < 4; ++i) r += sh[i];
  return r;
}
__device__ __forceinline__ float block_maxr(float v, float* sh){
  #pragma unroll
  for (int o = 32; o; o >>= 1) v = fmaxf(v, __shfl_down(v, o, 64));
  int wv = threadIdx.x >> 6, ln = threadIdx.x & 63;
  __syncthreads();
  if (ln == 0) sh[wv] = v;
  __syncthreads();
  float r = sh[0];
  for (int i = 1; i < 4; ++i) r = fmaxf(r, sh[i]);
  return r;
}

// ---------------- f32 GEMM 128x128 (8x8/thread, BK=8, reg-prefetch) ----------------
__global__ __launch_bounds__(256) void gemm_f32(
    const float* __restrict__ A, const float* __restrict__ W, float* __restrict__ C,
    int M, int N, int K, int lda, int ldw, int ldc,
    long long sAo, long long sAi, int inner,
    long long sWo, long long sWi,
    long long sCo, long long sCi,
    const float* __restrict__ bias, int bis,
    const float* __restrict__ rscale, int rs_shift,
    const int* __restrict__ gather, int wt, int ntiles)
{
  __shared__ float As[8][132];
  __shared__ float Bs[8][132];
  int bz = blockIdx.y;
  int oz = bz / inner, iz = bz - oz * inner;
  const float* Ab = A + (size_t)oz * sAo + (size_t)iz * sAi;
  const float* Wb = W + (size_t)oz * sWo + (size_t)iz * sWi;
  float* Cb = C + (size_t)oz * sCo + (size_t)iz * sCi;
  const float* bp = bias ? bias + (size_t)iz * bis : nullptr;

  int mt = blockIdx.x / ntiles, nt = blockIdx.x - mt * ntiles;
  int t = threadIdx.x;
  int tr = t >> 4, tc = t & 15;

  float acc[8][8];
  #pragma unroll
  for (int i = 0; i < 8; ++i)
    #pragma unroll
    for (int j = 0; j < 8; ++j) acc[i][j] = 0.f;

  int arow = t >> 1, akq = (t & 1) * 4;
  int ra = imin(mt * 128 + arow, M - 1);
  if (gather) ra = gather[ra];
  const float* pA = Ab + (size_t)ra * lda + akq;
  int brow = t >> 1, bkq = (t & 1) * 4;
  int rb = imin(nt * 128 + brow, N - 1);
  const float* pB1 = Wb + (size_t)rb * ldw + bkq;
  int bkk = t >> 5, bcol = (t & 31) * 4;
  const float* pB0 = Wb + (size_t)bkk * ldw + nt * 128 + bcol;

  // prefetch tile 0
  f32x4 a_pre = *(const f32x4*)(pA);
  f32x4 b_pre = wt ? *(const f32x4*)(pB1) : *(const f32x4*)(pB0);

  for (int kt = 0; kt < K; kt += 8){
    #pragma unroll
    for (int z = 0; z < 4; ++z) As[akq + z][arow] = a_pre[z];
    if (wt){
      #pragma unroll
      for (int z = 0; z < 4; ++z) Bs[bkq + z][brow] = b_pre[z];
    } else {
      #pragma unroll
      for (int z = 0; z < 4; ++z) Bs[bkk][bcol + z] = b_pre[z];
    }
    __syncthreads();
    if (kt + 8 < K){
      a_pre = *(const f32x4*)(pA + kt + 8);
      b_pre = wt ? *(const f32x4*)(pB1 + kt + 8)
                 : *(const f32x4*)(pB0 + (size_t)(kt + 8) * ldw);
    }
    #pragma unroll
    for (int kk = 0; kk < 8; ++kk){
      f32x4 a0 = *(const f32x4*)&As[kk][tr * 8];
      f32x4 a1 = *(const f32x4*)&As[kk][tr * 8 + 4];
      f32x4 b0 = *(const f32x4*)&Bs[kk][tc * 8];
      f32x4 b1 = *(const f32x4*)&Bs[kk][tc * 8 + 4];
      #pragma unroll
      for (int i = 0; i < 4; ++i){
        #pragma unroll
        for (int j = 0; j < 4; ++j){
          acc[i][j]         += a0[i] * b0[j];
          acc[i][j + 4]     += a0[i] * b1[j];
          acc[i + 4][j]     += a1[i] * b0[j];
          acc[i + 4][j + 4] += a1[i] * b1[j];
        }
      }
    }
    __syncthreads();
  }

  #pragma unroll
  for (int i = 0; i < 8; ++i){
    int row = mt * 128 + tr * 8 + i;
    if (row >= M) continue;
    float rs = rscale ? rscale[row >> rs_shift] : 1.f;
    #pragma unroll
    for (int j = 0; j < 8; ++j){
      int col = nt * 128 + tc * 8 + j;
      float v = acc[i][j];
      if (bp) v += bp[col];
      Cb[(size_t)row * ldc + col] = v * rs;
    }
  }
}

// ---------------- f32 GEMM 128x64 (8x4/thread, BK=16, reg-prefetch) ----------------
__global__ __launch_bounds__(256) void gemm_f32b(
    const float* __restrict__ A, const float* __restrict__ W, float* __restrict__ C,
    int M, int N, int K, int lda, int ldw, int ldc,
    long long sAo, long long sAi, int inner,
    long long sWo, long long sWi,
    long long sCo, long long sCi,
    const float* __restrict__ bias, int bis,
    const float* __restrict__ rscale, int rs_shift,
    const int* __restrict__ gather, int wt, int ntiles)
{
  __shared__ float As[16][132];
  __shared__ float Bs[16][68];
  int bz = blockIdx.y;
  int oz = bz / inner, iz = bz - oz * inner;
  const float* Ab = A + (size_t)oz * sAo + (size_t)iz * sAi;
  const float* Wb = W + (size_t)oz * sWo + (size_t)iz * sWi;
  float* Cb = C + (size_t)oz * sCo + (size_t)iz * sCi;
  const float* bp = bias ? bias + (size_t)iz * bis : nullptr;

  int mt = blockIdx.x / ntiles, nt = blockIdx.x - mt * ntiles;
  int t = threadIdx.x;
  int tr = t >> 4, tc = t & 15;

  float acc[8][4];
  #pragma unroll
  for (int i = 0; i < 8; ++i)
    #pragma unroll
    for (int j = 0; j < 4; ++j) acc[i][j] = 0.f;

  int arow = t >> 1, akq = (t & 1) * 8;
  int ra = imin(mt * 128 + arow, M - 1);
  if (gather) ra = gather[ra];
  const float* pA = Ab + (size_t)ra * lda + akq;
  int brow = t >> 2, bkq = (t & 3) * 4;
  int rb = imin(nt * 64 + brow, N - 1);
  const float* pB1 = Wb + (size_t)rb * ldw + bkq;
  int bkk = t >> 4, bcol = (t & 15) * 4;
  const float* pB0 = Wb + (size_t)bkk * ldw + nt * 64 + bcol;

  f32x4 a_pre0 = *(const f32x4*)(pA);
  f32x4 a_pre1 = *(const f32x4*)(pA + 4);
  f32x4 b_pre  = wt ? *(const f32x4*)(pB1) : *(const f32x4*)(pB0);

  for (int kt = 0; kt < K; kt += 16){
    #pragma unroll
    for (int z = 0; z < 4; ++z){ As[akq + z][arow] = a_pre0[z]; As[akq + 4 + z][arow] = a_pre1[z]; }
    if (wt){
      #pragma unroll
      for (int z = 0; z < 4; ++z) Bs[bkq + z][brow] = b_pre[z];
    } else {
      #pragma unroll
      for (int z = 0; z < 4; ++z) Bs[bkk][bcol + z] = b_pre[z];
    }
    __syncthreads();
    if (kt + 16 < K){
      a_pre0 = *(const f32x4*)(pA + kt + 16);
      a_pre1 = *(const f32x4*)(pA + kt + 20);
      b_pre  = wt ? *(const f32x4*)(pB1 + kt + 16)
                  : *(const f32x4*)(pB0 + (size_t)(kt + 16) * ldw);
    }
    #pragma unroll
    for (int kk = 0; kk < 16; ++kk){
      f32x4 a0 = *(const f32x4*)&As[kk][tr * 8];
      f32x4 a1 = *(const f32x4*)&As[kk][tr * 8 + 4];
      f32x4 b0 = *(const f32x4*)&Bs[kk][tc * 4];
      #pragma unroll
      for (int i = 0; i < 4; ++i){
        #pragma unroll
        for (int j = 0; j < 4; ++j){
          acc[i][j]     += a0[i] * b0[j];
          acc[i + 4][j] += a1[i] * b0[j];
        }
      }
    }
    __syncthreads();
  }

  #pragma unroll
  for (int i = 0; i < 8; ++i){
    int row = mt * 128 + tr * 8 + i;
    if (row >= M) continue;
    float rs = rscale ? rscale[row >> rs_shift] : 1.f;
    #pragma unroll
    for (int j = 0; j < 4; ++j){
      int col = nt * 64 + tc * 4 + j;
      float v = acc[i][j];
      if (bp) v += bp[col];
      Cb[(size_t)row * ldc + col] = v * rs;
    }
  }
}

// ---------------- LayerNorm f32 -> kvf slot rows ----------------
__global__ __launch_bounds__(256) void ln_f32(
    const float* __restrict__ state, const float* __restrict__ g,
    const float* __restrict__ be, float* __restrict__ kvf)
{
  int row = blockIdx.x;
  int b = row >> 7, s = row & 127;
  const float* xp = state + (size_t)row * 512;
  int t = threadIdx.x;
  float x0 = xp[t], x1 = xp[t + 256];
  __shared__ float sh[4];
  float sx  = block_sum(x0 + x1, sh);
  float sxx = block_sum(x0 * x0 + x1 * x1, sh);
  float mu = sx * (1.f / 512.f);
  float var = fmaxf(sxx * (1.f / 512.f) - mu * mu, 0.f);
  float rstd = rsqrtf(var + 1e-5f);
  float* o = kvf + (size_t)b * 327680 + (size_t)(512 + s) * 512;
  o[t]       = (x0 - mu) * rstd * g[t]       + be[t];
  o[t + 256] = (x1 - mu) * rstd * g[t + 256] + be[t + 256];
}

// ---------------- f32 softmax, in-place, 640 cols ----------------
__global__ __launch_bounds__(256) void softmax_f32(float* __restrict__ sc, float scale)
{
  size_t row = blockIdx.x;
  float* sp = sc + row * 640;
  int t = threadIdx.x;
  float v0 = sp[t], v1 = sp[t + 256];
  float v2 = (t < 128) ? sp[t + 512] : -3.0e38f;
  __shared__ float sh[4];
  float m = block_maxr(fmaxf(fmaxf(v0, v1), v2), sh);
  float e0 = expf((v0 - m) * scale), e1 = expf((v1 - m) * scale);
  float e2 = (t < 128) ? expf((v2 - m) * scale) : 0.f;
  float ssum = block_sum(e0 + e1 + e2, sh);
  float inv = 1.f / ssum;
  sp[t] = e0 * inv;
  sp[t + 256] = e1 * inv;
  if (t < 128) sp[t + 512] = e2 * inv;
}

// ---------------- read-gate scores (exact f32) ----------------
__global__ __launch_bounds__(64) void rscore_k(
    const float* __restrict__ state, const float* __restrict__ rw,
    const float* __restrict__ rb, float* __restrict__ rsc)
{
  int row = blockIdx.x, l = threadIdx.x;
  const float* sp = state + (size_t)row * 512;
  float a = 0.f;
  for (int d = l; d < 512; d += 64) a += sp[d] * rw[d];
  #pragma unroll
  for (int o = 32; o; o >>= 1) a += __shfl_down(a, o, 64);
  if (l == 0) rsc[row] = a + rb[0];
}

// ---------------- top-8 read indices ----------------
__global__ void topk_read(const float* __restrict__ sc, float* __restrict__ out_idx)
{
  int b = threadIdx.x; if (b >= 64) return;
  const float* p = sc + b * 128;
  unsigned long long u0 = 0, u1 = 0;
  for (int it = 0; it < 8; ++it){
    float best = -3.0e38f; int bi = 0;
    for (int j = 0; j < 128; ++j){
      bool used = (j < 64) ? ((u0 >> j) & 1) : ((u1 >> (j - 64)) & 1);
      float v = p[j];
      if (!used && v > best){ best = v; bi = j; }
    }
    if (bi < 64) u0 |= 1ull << bi; else u1 |= 1ull << (bi - 64);
    out_idx[b * 8 + it] = (float)bi;
  }
}

// ---------------- gate f32 ----------------
__global__ __launch_bounds__(256) void gate_f32(
    const float* __restrict__ aout, const float* __restrict__ gw, const float* __restrict__ gb,
    float* __restrict__ out_eidx, float* __restrict__ out_ew, float* __restrict__ gscale)
{
  int b = blockIdx.x, t = threadIdx.x;
  __shared__ float mean[512];
  __shared__ float lg[64];
  const float* ap = aout + (size_t)b * 65536;
  float s0 = 0.f, s1 = 0.f;
  for (int s = 0; s < 128; ++s){
    s0 += ap[s * 512 + t];
    s1 += ap[s * 512 + t + 256];
  }
  mean[t] = s0 * (1.f / 128.f);
  mean[t + 256] = s1 * (1.f / 128.f);
  __syncthreads();
  if (t < 64){
    float acc = gb[t];
    const float* gwr = gw + t * 512;
    for (int d = 0; d < 512; ++d) acc += mean[d] * gwr[d];
    lg[t] = acc;
  }
  __syncthreads();
  if (t == 0){
    int i0 = 0; float v0 = lg[0];
    for (int e = 1; e < 64; ++e) if (lg[e] > v0){ v0 = lg[e]; i0 = e; }
    int i1 = (i0 == 0) ? 1 : 0; float v1 = lg[i1];
    for (int e = 0; e < 64; ++e) if (e != i0 && lg[e] > v1){ v1 = lg[e]; i1 = e; }
    float e1 = expf(v1 - v0);
    float w0 = 1.f / (1.f + e1), w1 = e1 / (1.f + e1);
    out_eidx[b * 2]     = (float)i0;
    out_eidx[b * 2 + 1] = (float)i1;
    out_ew[b * 2]     = w0;
    out_ew[b * 2 + 1] = w1;
    gscale[b] = w0 + w1;
  }
}

// ---------------- slot-gate scores f32 ----------------
__global__ void slot_scores_f32(
    const float* __restrict__ eout, const float* __restrict__ sgw,
    const float* __restrict__ sgb, float* __restrict__ ssc)
{
  int row = blockIdx.x, l = threadIdx.x;
  const float* ep = eout + (size_t)row * 512;
  float a = 0.f;
  for (int d = l; d < 512; d += 64) a += ep[d] * sgw[d];
  #pragma unroll
  for (int o = 32; o; o >>= 1) a += __shfl_down(a, o, 64);
  if (l == 0) ssc[row] = a + sgb[0];
}

// ---------------- top-8 slots ----------------
__global__ void topk_slot(const float* __restrict__ sc, float* __restrict__ out_idx,
                          float* __restrict__ out_w, int* __restrict__ rowmap,
                          float* __restrict__ slotw_f)
{
  int b = threadIdx.x; if (b >= 64) return;
  const float* p = sc + b * 128;
  unsigned long long u0 = 0, u1 = 0;
  float vals[8]; int idx[8];
  for (int it = 0; it < 8; ++it){
    float best = -3.0e38f; int bi = 0;
    for (int j = 0; j < 128; ++j){
      bool used = (j < 64) ? ((u0 >> j) & 1) : ((u1 >> (j - 64)) & 1);
      float v = p[j];
      if (!used && v > best){ best = v; bi = j; }
    }
    if (bi < 64) u0 |= 1ull << bi; else u1 |= 1ull << (bi - 64);
    vals[it] = best; idx[it] = bi;
  }
  float m = vals[0], s = 0.f, e[8];
  for (int i = 0; i < 8; ++i){ e[i] = expf(vals[i] - m); s += e[i]; }
  float inv = 1.f / s;
  for (int i = 0; i < 8; ++i){
    float w = e[i] * inv;
    out_idx[b * 8 + i] = (float)idx[i];
    out_w[b * 8 + i]   = w;
    rowmap[b * 8 + i]  = b * 128 + idx[i];
    slotw_f[b * 8 + i] = w;
  }
}

// ---------------- scatter: f32 ns output + bf16 ns ----------------
__global__ __launch_bounds__(256) void finalize2_k(
    const float* __restrict__ upd, const int* __restrict__ rowmap,
    const float* __restrict__ slotw, const float* __restrict__ raw_state,
    float* __restrict__ nsf, u16* __restrict__ nsb)
{
  int m = blockIdx.x, t = threadIdx.x;
  int row = rowmap[m];
  float w = slotw[m];
  #pragma unroll
  for (int d = t; d < 512; d += 256){
    float st = raw_state[(size_t)row * 512 + d];
    float v = 0.7f * st + 0.3f * w * tanhf(upd[(size_t)m * 512 + d]);
    nsf[(size_t)row * 512 + d] = v;
    nsb[(size_t)row * 512 + d] = f2bf(v);
  }
}

// ---------------- bf16 MFMA GEMM (final output; verified) ----------------
__global__ __launch_bounds__(256) void gemm_bt(
    const u16* __restrict__ A, const u16* __restrict__ W, void* __restrict__ C,
    int M, int N, int K, int lda, int ldw, int ldc,
    long long sAo, long long sAi, int inner,
    long long sWo, long long sWi,
    long long sCo, long long sCi,
    const u16* __restrict__ bias, int bias_row,
    const float* __restrict__ rscale, int rs_shift,
    const int* __restrict__ gather,
    float oscale, int cf32, int ntiles)
{
  __shared__ __align__(16) u16 lA[128 * 32];
  __shared__ __align__(16) u16 lB[128 * 32];

  int bz = blockIdx.y;
  int oz = bz / inner, iz = bz - oz * inner;
  const u16* Ab = A + (size_t)oz * sAo + (size_t)iz * sAi;
  const u16* Wb = W + (size_t)oz * sWo + (size_t)iz * sWi;
  char* Cb = (char*)C + ((size_t)oz * sCo + (size_t)iz * sCi) * (cf32 ? 4 : 2);

  int mt = blockIdx.x / ntiles, nt = blockIdx.x - mt * ntiles;

  int tid = threadIdx.x;
  int wave = tid >> 6, lane = tid & 63;
  int wm = (wave >> 1) * 64, wn = (wave & 1) * 64;
  int fr = lane & 15, fq = lane >> 4;

  int m0  = tid >> 2, kc = tid & 3;
  int rA0 = imin(mt * 128 + m0,      M - 1);
  int rA1 = imin(mt * 128 + m0 + 64, M - 1);
  if (gather){ rA0 = gather[rA0]; rA1 = gather[rA1]; }
  int rB0 = imin(nt * 128 + m0,      N - 1);
  int rB1 = imin(nt * 128 + m0 + 64, N - 1);
  const u16* pA0 = Ab + (size_t)rA0 * lda + kc * 8;
  const u16* pA1 = Ab + (size_t)rA1 * lda + kc * 8;
  const u16* pB0 = Wb + (size_t)rB0 * ldw + kc * 8;
  const u16* pB1 = Wb + (size_t)rB1 * ldw + kc * 8;
  char* dA0 = (char*)lA + wave * 1024;
  char* dA1 = (char*)lA + 4096 + wave * 1024;
  char* dB0 = (char*)lB + wave * 1024;
  char* dB1 = (char*)lB + 4096 + wave * 1024;

  f32x4 zero = {0.f, 0.f, 0.f, 0.f};
  f32x4 acc[4][4];
  #pragma unroll
  for (int i = 0; i < 4; ++i)
    #pragma unroll
    for (int j = 0; j < 4; ++j) acc[i][j] = zero;

  for (int kt = 0; kt < K; kt += 32){
    gl_lds16(pA0 + kt, dA0);
    gl_lds16(pA1 + kt, dA1);
    gl_lds16(pB0 + kt, dB0);
    gl_lds16(pB1 + kt, dB1);
    __syncthreads();

    short8 afr[4], bfr[4];
    #pragma unroll
    for (int i = 0; i < 4; ++i){
      afr[i] = *(const short8*)&lA[(wm + i * 16 + fr) * 32 + fq * 8];
      bfr[i] = *(const short8*)&lB[(wn + i * 16 + fr) * 32 + fq * 8];
    }
    #pragma unroll
    for (int i = 0; i < 4; ++i)
      #pragma unroll
      for (int j = 0; j < 4; ++j)
        acc[i][j] = __builtin_amdgcn_mfma_f32_16x16x32_bf16(afr[i], bfr[j], acc[i][j], 0, 0, 0);
    __syncthreads();
  }

  #pragma unroll
  for (int i = 0; i < 4; ++i){
    #pragma unroll
    for (int j = 0; j < 4; ++j){
      #pragma unroll
      for (int r = 0; r < 4; ++r){
        int row = mt * 128 + wm + i * 16 + fq * 4 + r;
        int col = nt * 128 + wn + j * 16 + fr;
        if (row < M){
          float v = acc[i][j][r] * oscale;
          if (bias)   v += bf2f(bias[bias_row ? row : col]);
          if (rscale) v *= rscale[row >> rs_shift];
          size_t idx = (size_t)row * ldc + col;
          if (cf32) ((float*)Cb)[idx] = v;
          else      ((u16*)Cb)[idx]   = f2bf(v);
        }
      }
    }
  }
}

// ---------------- final out reduce ----------------
__global__ __launch_bounds__(256) void out_reduce(
    const float* __restrict__ part, const float* __restrict__ ob, float* __restrict__ out)
{
  int i = blockIdx.x * 256 + threadIdx.x;
  float a = ob[i & 511];
  for (int ks = 0; ks < 64; ++ks) a += part[(size_t)ks * 32768 + i];
  out[i] = a;
}

// ---------------- host helpers ----------------
static inline int hmin(int a, int b){ return a < b ? a : b; }

static inline void gemmF(hipStream_t st, const float* A, const float* W, float* C,
    int M, int N, int K, int lda, int ldw, int ldc,
    long long sAo, long long sAi, int inner,
    long long sWo, long long sWi, long long sCo, long long sCi, int batch,
    const float* bias, int bis, const float* rs, int rss, const int* gth, int wt)
{
  int mt = (M + 127) / 128, nt = (N + 127) / 128;
  gemm_f32<<<dim3(mt * nt, batch), dim3(256), 0, st>>>(
      A, W, C, M, N, K, lda, ldw, ldc, sAo, sAi, inner, sWo, sWi, sCo, sCi,
      bias, bis, rs, rss, gth, wt, nt);
}
static inline void gemmFb(hipStream_t st, const float* A, const float* W, float* C,
    int M, int N, int K, int lda, int ldw, int ldc,
    long long sAo, long long sAi, int inner,
    long long sWo, long long sWi, long long sCo, long long sCi, int batch,
    const float* bias, int bis, const float* rs, int rss, const int* gth, int wt)
{
  int mt = (M + 127) / 128, nt = (N + 63) / 64;
  gemm_f32b<<<dim3(mt * nt, batch), dim3(256), 0, st>>>(
      A, W, C, M, N, K, lda, ldw, ldc, sAo, sAi, inner, sWo, sWi, sCo, sCi,
      bias, bis, rs, rss, gth, wt, nt);
}
static inline void conv(hipStream_t st, const void* src, u16* dst, long long n){
  int blocks = hmin((int)((n + 255) / 256), 4096);
  conv_k<<<dim3(blocks), dim3(256), 0, st>>>((const float*)src, dst, n);
}

extern "C" void kernel_launch(void* const* d_in, const int* in_sizes, int n_in,
                              void* d_out, int out_size, void* d_ws, size_t ws_size,
                              hipStream_t stream)
{
  float* fo = (float*)d_out;

  static const int expect_sizes[22] = {
    16777216, 4194304, 262144, 512, 512, 512, 786432, 1536, 262144, 512,
    262144, 512, 32768, 64, 512, 1, 512, 1, 262144, 512, 33554432, 512 };
  bool ok = (n_in == 22);
  if (ok) for (int i = 0; i < 22; ++i) if (in_sizes[i] != expect_sizes[i]) ok = false;
  if (!ok){ fill_f32<<<dim3(128), dim3(256), 0, stream>>>(fo, 29.f * 1024.f); return; }
  if (out_size != 4228864){ fill_f32<<<dim3(128), dim3(256), 0, stream>>>(fo, 30.f * 1024.f); return; }

  const float* xR     = (const float*)d_in[0];
  const float* stateR = (const float*)d_in[1];
  const float* inwR   = (const float*)d_in[2];
  const float* inbR   = (const float*)d_in[3];
  const float* lngR   = (const float*)d_in[4];
  const float* lnbR   = (const float*)d_in[5];
  const float* ainwR  = (const float*)d_in[6];
  const float* ainbR  = (const float*)d_in[7];
  const float* aowR   = (const float*)d_in[8];
  const float* aobR   = (const float*)d_in[9];
  const float* expwR  = (const float*)d_in[10];
  const float* expbR  = (const float*)d_in[11];
  const float* gwR    = (const float*)d_in[12];
  const float* gbR    = (const float*)d_in[13];
  const float* rwR    = (const float*)d_in[14];
  const float* rbR    = (const float*)d_in[15];
  const float* sgwR   = (const float*)d_in[16];
  const float* sgbR   = (const float*)d_in[17];
  const float* stwR   = (const float*)d_in[18];
  const float* stbR   = (const float*)d_in[19];
  const float* outwR  = (const float*)d_in[20];
  const float* outbR  = (const float*)d_in[21];

  float* outp  = fo;
  float* nsf   = fo + 32768;
  float* sidx  = fo + 4227072;
  float* ridx  = fo + 4227584;
  float* eidx  = fo + 4228096;
  float* swout = fo + 4228224;
  float* ewout = fo + 4228736;

  char* wsp = (char*)d_ws;
  size_t o = 0;
  auto alloc = [&](size_t bytes){ size_t r = o; o += (bytes + 255) & ~(size_t)255; return r; };
  float* kvf    = (float*)(wsp + alloc(83886080));
  float* qf     = (float*)(wsp + alloc(16777216));
  float* qkpv   = (float*)(wsp + alloc(16777216));
  float* scoresb= (float*)(wsp + alloc(20971520));
  float* attnf  = (float*)(wsp + alloc(16777216));
  float* opart  = (float*)(wsp + alloc(8388608));
  float* updf   = (float*)(wsp + alloc(1048576));
  float* ainwT  = (float*)(wsp + alloc(1048576));
  float* rsc    = (float*)(wsp + alloc(32768));
  float* ssc    = (float*)(wsp + alloc(32768));
  float* gscale = (float*)(wsp + alloc(256));
  int*   rowmap = (int*)  (wsp + alloc(2048));
  float* slotw  = (float*)(wsp + alloc(2048));
  u16* nsb      = (u16*)  (wsp + alloc(8388608));

  u16*   out_w_c = (u16*)kvf;
  float* aoutf   = qf;
  float* eoutf   = attnf;

  if (ws_size < o){ fill_f32<<<dim3(128), dim3(256), 0, stream>>>(fo, 31.f * 1024.f); return; }

  transp_f32<<<dim3(64), dim3(256), 0, stream>>>(ainwR, ainwT);
  conv(stream, stateR, nsb, 4194304);

  // 1) LayerNorm -> kvf slots ; read-gate
  ln_f32<<<dim3(8192), dim3(256), 0, stream>>>(stateR, lngR, lnbR, kvf);
  rscore_k<<<dim3(8192), dim3(64), 0, stream>>>(stateR, rwR, rbR, rsc);
  topk_read<<<dim3(1), dim3(64), 0, stream>>>(rsc, ridx);
  // 2) x_proj -> kvf rows 0..511
  gemmF(stream, xR, inwR, kvf, 512, 512, 512, 512, 512, 512,
        262144, 0, 1, 0, 0, 327680, 0, 64, inbR, 0, nullptr, 0, nullptr, 1);
  // 3) q -> qf
  gemmFb(stream, kvf + 262144, ainwR, qf, 128, 512, 512, 512, 512, 512,
        327680, 0, 1, 0, 0, 65536, 0, 64, ainbR, 0, nullptr, 0, nullptr, 1);
  // 4) attention (GEMM factorization), chunks of 16 batches
  for (int cb = 0; cb < 4; ++cb){
    const float* qc  = qf  + (size_t)cb * 16 * 65536;
    const float* kvc = kvf + (size_t)cb * 16 * 327680;
    float* atc = attnf + (size_t)cb * 16 * 65536;
    gemmFb(stream, qc, ainwT, qkpv, 128, 512, 128, 512, 512, 512,
          65536, 128, 4, 0, 128, 262144, 65536, 64,
          nullptr, 0, nullptr, 0, nullptr, 1);
    gemmFb(stream, qkpv, kvc, scoresb, 128, 640, 512, 512, 512, 640,
          262144, 65536, 4, 327680, 0, 327680, 81920, 64,
          nullptr, 0, nullptr, 0, nullptr, 1);
    softmax_f32<<<dim3(8192), dim3(256), 0, stream>>>(scoresb, 0.08838834764831845f);
    gemmFb(stream, scoresb, kvc, qkpv, 128, 512, 640, 640, 512, 512,
          327680, 81920, 4, 327680, 0, 262144, 65536, 64,
          nullptr, 0, nullptr, 0, nullptr, 0);
    gemmFb(stream, qkpv, ainwR + (size_t)1024 * 512, atc, 128, 128, 512, 512, 512, 512,
          262144, 65536, 4, 0, 65536, 65536, 128, 64,
          ainbR + 1024, 128, nullptr, 0, nullptr, 1);
  }
  // 5) attn_out
  gemmF(stream, attnf, aowR, aoutf, 8192, 512, 512, 512, 512, 512,
        0, 0, 1, 0, 0, 0, 0, 1, aobR, 0, nullptr, 0, nullptr, 1);
  // 6) gate
  gate_f32<<<dim3(64), dim3(256), 0, stream>>>(aoutf, gwR, gbR, eidx, ewout, gscale);
  // 7) expert_out
  gemmF(stream, aoutf, expwR, eoutf, 8192, 512, 512, 512, 512, 512,
        0, 0, 1, 0, 0, 0, 0, 1, expbR, 0, gscale, 7, nullptr, 1);
  // 8) slot scores + top-8
  slot_scores_f32<<<dim3(8192), dim3(64), 0, stream>>>(eoutf, sgwR, sgbR, ssc);
  topk_slot<<<dim3(1), dim3(64), 0, stream>>>(ssc, sidx, swout, rowmap, slotw);
  // 9) upd
  gemmFb(stream, eoutf, stwR, updf, 512, 512, 512, 512, 512, 512,
        0, 0, 1, 0, 0, 0, 0, 1, stbR, 0, nullptr, 0, rowmap, 1);
  // 10) next_state
  copyf32_k<<<dim3(4096), dim3(256), 0, stream>>>((const uint4*)stateR, (uint4*)nsf);
  finalize2_k<<<dim3(512), dim3(256), 0, stream>>>(updf, rowmap, slotw, stateR, nsf, nsb);
  // 11) out_w -> bf16 (overlays kvf)
  conv(stream, outwR, out_w_c, 33554432);
  // 12) final output GEMM (bf16 MFMA) + reduce
  gemm_bt<<<dim3(4, 64), dim3(256), 0, stream>>>(
      nsb, out_w_c, opart, 64, 512, 1024, 65536, 65536, 512,
      1024, 0, 1, 1024, 0, 32768, 0,
      nullptr, 0, nullptr, 0, nullptr, 1.f, 1, 4);
  out_reduce<<<dim3(128), dim3(256), 0, stream>>>(opart, outbR, outp);
}

// Round 19
// 1608.925 us; speedup vs baseline: 1.0871x; 1.0005x over previous
//
#include <hip/hip_runtime.h>
#include <stdint.h>

typedef unsigned short u16;
typedef __attribute__((ext_vector_type(8))) short short8;
typedef __attribute__((ext_vector_type(4))) float f32x4;

__device__ __forceinline__ float bf2f(u16 u){
  union { unsigned int i; float f; } v; v.i = ((unsigned int)u) << 16; return v.f;
}
__device__ __forceinline__ u16 f2bf(float f){
  union { float f; unsigned int i; } v; v.f = f;
  return (u16)((v.i + 0x7fffu + ((v.i >> 16) & 1u)) >> 16);
}
__device__ __forceinline__ int imin(int a, int b){ return a < b ? a : b; }

__device__ __forceinline__ void gl_lds16(const void* g, void* l){
  __builtin_amdgcn_global_load_lds(
      (const __attribute__((address_space(1))) void*)g,
      (__attribute__((address_space(3))) void*)l, 16, 0, 0);
}

// ---------------- f32 -> bf16 conversion ----------------
__global__ __launch_bounds__(256) void conv_k(const float* __restrict__ src,
                                              u16* __restrict__ dst, long long n){
  long long i = (long long)blockIdx.x * 256 + threadIdx.x;
  long long st = (long long)gridDim.x * 256;
  for (; i < n; i += st) dst[i] = f2bf(src[i]);
}
__global__ __launch_bounds__(256) void fill_f32(float* __restrict__ p, float val){
  int i = blockIdx.x * 256 + threadIdx.x;
  if (i < 32768) p[i] = val;
}
__global__ __launch_bounds__(256) void copyf32_k(const uint4* __restrict__ s, uint4* __restrict__ d){
  size_t i = (size_t)blockIdx.x * blockDim.x + threadIdx.x;
  d[i] = s[i];
}

// ---------------- f32 transpose of ain_w K-slice ----------------
__global__ __launch_bounds__(256) void transp_f32(const float* __restrict__ w,
                                                  float* __restrict__ o){
  __shared__ float sh[64][65];
  int bd = blockIdx.x & 7, bc = blockIdx.x >> 3;
  int t = threadIdx.x;
  int lane = t & 63, r4 = t >> 6;
  #pragma unroll
  for (int r = 0; r < 64; r += 4){
    int dd = r + r4, cc = lane;
    sh[dd][cc] = w[(size_t)(512 + bd * 64 + dd) * 512 + bc * 64 + cc];
  }
  __syncthreads();
  #pragma unroll
  for (int r = 0; r < 64; r += 4){
    int cc = r + r4, dd = lane;
    o[(size_t)(bc * 64 + cc) * 512 + bd * 64 + dd] = sh[dd][cc];
  }
}

// ---------------- block reduce ----------------
__device__ __forceinline__ float block_sum(float v, float* sh){
  #pragma unroll
  for (int o = 32; o; o >>= 1) v += __shfl_down(v, o, 64);
  int wv = threadIdx.x >> 6, ln = threadIdx.x & 63;
  __syncthreads();
  if (ln == 0) sh[wv] = v;
  __syncthreads();
  float r = 0.f;
  for (int i = 0; i < 4; ++i) r += sh[i];
  return r;
}
__device__ __forceinline__ float block_maxr(float v, float* sh){
  #pragma unroll
  for (int o = 32; o; o >>= 1) v = fmaxf(v, __shfl_down(v, o, 64));
  int wv = threadIdx.x >> 6, ln = threadIdx.x & 63;
  __syncthreads();
  if (ln == 0) sh[wv] = v;
  __syncthreads();
  float r = sh[0];
  for (int i = 1; i < 4; ++i) r = fmaxf(r, sh[i]);
  return r;
}

// ---------------- f32 GEMM 128x128 (8x8/thread, BK=8, dbuf LDS, 1 barrier) ----------------
__global__ __launch_bounds__(256) void gemm_f32(
    const float* __restrict__ A, const float* __restrict__ W, float* __restrict__ C,
    int M, int N, int K, int lda, int ldw, int ldc,
    long long sAo, long long sAi, int inner,
    long long sWo, long long sWi,
    long long sCo, long long sCi,
    const float* __restrict__ bias, int bis,
    const float* __restrict__ rscale, int rs_shift,
    const int* __restrict__ gather, int wt, int ntiles)
{
  __shared__ float As[2][8][132];
  __shared__ float Bs[2][8][132];
  int bz = blockIdx.y;
  int oz = bz / inner, iz = bz - oz * inner;
  const float* Ab = A + (size_t)oz * sAo + (size_t)iz * sAi;
  const float* Wb = W + (size_t)oz * sWo + (size_t)iz * sWi;
  float* Cb = C + (size_t)oz * sCo + (size_t)iz * sCi;
  const float* bp = bias ? bias + (size_t)iz * bis : nullptr;

  int mt = blockIdx.x / ntiles, nt = blockIdx.x - mt * ntiles;
  int t = threadIdx.x;
  int tr = t >> 4, tc = t & 15;

  float acc[8][8];
  #pragma unroll
  for (int i = 0; i < 8; ++i)
    #pragma unroll
    for (int j = 0; j < 8; ++j) acc[i][j] = 0.f;

  int arow = t >> 1, akq = (t & 1) * 4;
  int ra = imin(mt * 128 + arow, M - 1);
  if (gather) ra = gather[ra];
  const float* pA = Ab + (size_t)ra * lda + akq;
  int brow = t >> 1, bkq = (t & 1) * 4;
  int rb = imin(nt * 128 + brow, N - 1);
  const float* pB1 = Wb + (size_t)rb * ldw + bkq;
  int bkk = t >> 5, bcol = (t & 31) * 4;
  const float* pB0 = Wb + (size_t)bkk * ldw + nt * 128 + bcol;

  // stage tile 0 into buffer 0
  {
    f32x4 a0 = *(const f32x4*)(pA);
    f32x4 b0 = wt ? *(const f32x4*)(pB1) : *(const f32x4*)(pB0);
    #pragma unroll
    for (int z = 0; z < 4; ++z) As[0][akq + z][arow] = a0[z];
    if (wt){
      #pragma unroll
      for (int z = 0; z < 4; ++z) Bs[0][bkq + z][brow] = b0[z];
    } else {
      #pragma unroll
      for (int z = 0; z < 4; ++z) Bs[0][bkk][bcol + z] = b0[z];
    }
  }
  __syncthreads();

  int cur = 0;
  for (int kt = 0; kt < K; kt += 8){
    bool more = (kt + 8 < K);
    f32x4 a_pre, b_pre;
    if (more){
      a_pre = *(const f32x4*)(pA + kt + 8);
      b_pre = wt ? *(const f32x4*)(pB1 + kt + 8)
                 : *(const f32x4*)(pB0 + (size_t)(kt + 8) * ldw);
    }
    #pragma unroll
    for (int kk = 0; kk < 8; ++kk){
      f32x4 a0 = *(const f32x4*)&As[cur][kk][tr * 8];
      f32x4 a1 = *(const f32x4*)&As[cur][kk][tr * 8 + 4];
      f32x4 b0 = *(const f32x4*)&Bs[cur][kk][tc * 8];
      f32x4 b1 = *(const f32x4*)&Bs[cur][kk][tc * 8 + 4];
      #pragma unroll
      for (int i = 0; i < 4; ++i){
        #pragma unroll
        for (int j = 0; j < 4; ++j){
          acc[i][j]         += a0[i] * b0[j];
          acc[i][j + 4]     += a0[i] * b1[j];
          acc[i + 4][j]     += a1[i] * b0[j];
          acc[i + 4][j + 4] += a1[i] * b1[j];
        }
      }
    }
    if (more){
      int nx = cur ^ 1;
      #pragma unroll
      for (int z = 0; z < 4; ++z) As[nx][akq + z][arow] = a_pre[z];
      if (wt){
        #pragma unroll
        for (int z = 0; z < 4; ++z) Bs[nx][bkq + z][brow] = b_pre[z];
      } else {
        #pragma unroll
        for (int z = 0; z < 4; ++z) Bs[nx][bkk][bcol + z] = b_pre[z];
      }
      __syncthreads();
      cur = nx;
    }
  }

  #pragma unroll
  for (int i = 0; i < 8; ++i){
    int row = mt * 128 + tr * 8 + i;
    if (row >= M) continue;
    float rs = rscale ? rscale[row >> rs_shift] : 1.f;
    #pragma unroll
    for (int j = 0; j < 8; ++j){
      int col = nt * 128 + tc * 8 + j;
      float v = acc[i][j];
      if (bp) v += bp[col];
      Cb[(size_t)row * ldc + col] = v * rs;
    }
  }
}

// ---------------- f32 GEMM 128x64 (8x4/thread, BK=16, dbuf LDS, 1 barrier) ----------------
__global__ __launch_bounds__(256) void gemm_f32b(
    const float* __restrict__ A, const float* __restrict__ W, float* __restrict__ C,
    int M, int N, int K, int lda, int ldw, int ldc,
    long long sAo, long long sAi, int inner,
    long long sWo, long long sWi,
    long long sCo, long long sCi,
    const float* __restrict__ bias, int bis,
    const float* __restrict__ rscale, int rs_shift,
    const int* __restrict__ gather, int wt, int ntiles)
{
  __shared__ float As[2][16][132];
  __shared__ float Bs[2][16][68];
  int bz = blockIdx.y;
  int oz = bz / inner, iz = bz - oz * inner;
  const float* Ab = A + (size_t)oz * sAo + (size_t)iz * sAi;
  const float* Wb = W + (size_t)oz * sWo + (size_t)iz * sWi;
  float* Cb = C + (size_t)oz * sCo + (size_t)iz * sCi;
  const float* bp = bias ? bias + (size_t)iz * bis : nullptr;

  int mt = blockIdx.x / ntiles, nt = blockIdx.x - mt * ntiles;
  int t = threadIdx.x;
  int tr = t >> 4, tc = t & 15;

  float acc[8][4];
  #pragma unroll
  for (int i = 0; i < 8; ++i)
    #pragma unroll
    for (int j = 0; j < 4; ++j) acc[i][j] = 0.f;

  int arow = t >> 1, akq = (t & 1) * 8;
  int ra = imin(mt * 128 + arow, M - 1);
  if (gather) ra = gather[ra];
  const float* pA = Ab + (size_t)ra * lda + akq;
  int brow = t >> 2, bkq = (t & 3) * 4;
  int rb = imin(nt * 64 + brow, N - 1);
  const float* pB1 = Wb + (size_t)rb * ldw + bkq;
  int bkk = t >> 4, bcol = (t & 15) * 4;
  const float* pB0 = Wb + (size_t)bkk * ldw + nt * 64 + bcol;

  // stage tile 0
  {
    f32x4 a0 = *(const f32x4*)(pA);
    f32x4 a1 = *(const f32x4*)(pA + 4);
    f32x4 b0 = wt ? *(const f32x4*)(pB1) : *(const f32x4*)(pB0);
    #pragma unroll
    for (int z = 0; z < 4; ++z){ As[0][akq + z][arow] = a0[z]; As[0][akq + 4 + z][arow] = a1[z]; }
    if (wt){
      #pragma unroll
      for (int z = 0; z < 4; ++z) Bs[0][bkq + z][brow] = b0[z];
    } else {
      #pragma unroll
      for (int z = 0; z < 4; ++z) Bs[0][bkk][bcol + z] = b0[z];
    }
  }
  __syncthreads();

  int cur = 0;
  for (int kt = 0; kt < K; kt += 16){
    bool more = (kt + 16 < K);
    f32x4 a_pre0, a_pre1, b_pre;
    if (more){
      a_pre0 = *(const f32x4*)(pA + kt + 16);
      a_pre1 = *(const f32x4*)(pA + kt + 20);
      b_pre  = wt ? *(const f32x4*)(pB1 + kt + 16)
                  : *(const f32x4*)(pB0 + (size_t)(kt + 16) * ldw);
    }
    #pragma unroll
    for (int kk = 0; kk < 16; ++kk){
      f32x4 a0 = *(const f32x4*)&As[cur][kk][tr * 8];
      f32x4 a1 = *(const f32x4*)&As[cur][kk][tr * 8 + 4];
      f32x4 b0 = *(const f32x4*)&Bs[cur][kk][tc * 4];
      #pragma unroll
      for (int i = 0; i < 4; ++i){
        #pragma unroll
        for (int j = 0; j < 4; ++j){
          acc[i][j]     += a0[i] * b0[j];
          acc[i + 4][j] += a1[i] * b0[j];
        }
      }
    }
    if (more){
      int nx = cur ^ 1;
      #pragma unroll
      for (int z = 0; z < 4; ++z){ As[nx][akq + z][arow] = a_pre0[z]; As[nx][akq + 4 + z][arow] = a_pre1[z]; }
      if (wt){
        #pragma unroll
        for (int z = 0; z < 4; ++z) Bs[nx][bkq + z][brow] = b_pre[z];
      } else {
        #pragma unroll
        for (int z = 0; z < 4; ++z) Bs[nx][bkk][bcol + z] = b_pre[z];
      }
      __syncthreads();
      cur = nx;
    }
  }

  #pragma unroll
  for (int i = 0; i < 8; ++i){
    int row = mt * 128 + tr * 8 + i;
    if (row >= M) continue;
    float rs = rscale ? rscale[row >> rs_shift] : 1.f;
    #pragma unroll
    for (int j = 0; j < 4; ++j){
      int col = nt * 64 + tc * 4 + j;
      float v = acc[i][j];
      if (bp) v += bp[col];
      Cb[(size_t)row * ldc + col] = v * rs;
    }
  }
}

// ---------------- LayerNorm f32 -> kvf slot rows ----------------
__global__ __launch_bounds__(256) void ln_f32(
    const float* __restrict__ state, const float* __restrict__ g,
    const float* __restrict__ be, float* __restrict__ kvf)
{
  int row = blockIdx.x;
  int b = row >> 7, s = row & 127;
  const float* xp = state + (size_t)row * 512;
  int t = threadIdx.x;
  float x0 = xp[t], x1 = xp[t + 256];
  __shared__ float sh[4];
  float sx  = block_sum(x0 + x1, sh);
  float sxx = block_sum(x0 * x0 + x1 * x1, sh);
  float mu = sx * (1.f / 512.f);
  float var = fmaxf(sxx * (1.f / 512.f) - mu * mu, 0.f);
  float rstd = rsqrtf(var + 1e-5f);
  float* o = kvf + (size_t)b * 327680 + (size_t)(512 + s) * 512;
  o[t]       = (x0 - mu) * rstd * g[t]       + be[t];
  o[t + 256] = (x1 - mu) * rstd * g[t + 256] + be[t + 256];
}

// ---------------- f32 softmax, in-place, 640 cols ----------------
__global__ __launch_bounds__(256) void softmax_f32(float* __restrict__ sc, float scale)
{
  size_t row = blockIdx.x;
  float* sp = sc + row * 640;
  int t = threadIdx.x;
  float v0 = sp[t], v1 = sp[t + 256];
  float v2 = (t < 128) ? sp[t + 512] : -3.0e38f;
  __shared__ float sh[4];
  float m = block_maxr(fmaxf(fmaxf(v0, v1), v2), sh);
  float e0 = expf((v0 - m) * scale), e1 = expf((v1 - m) * scale);
  float e2 = (t < 128) ? expf((v2 - m) * scale) : 0.f;
  float ssum = block_sum(e0 + e1 + e2, sh);
  float inv = 1.f / ssum;
  sp[t] = e0 * inv;
  sp[t + 256] = e1 * inv;
  if (t < 128) sp[t + 512] = e2 * inv;
}

// ---------------- read-gate scores (exact f32) ----------------
__global__ __launch_bounds__(64) void rscore_k(
    const float* __restrict__ state, const float* __restrict__ rw,
    const float* __restrict__ rb, float* __restrict__ rsc)
{
  int row = blockIdx.x, l = threadIdx.x;
  const float* sp = state + (size_t)row * 512;
  float a = 0.f;
  for (int d = l; d < 512; d += 64) a += sp[d] * rw[d];
  #pragma unroll
  for (int o = 32; o; o >>= 1) a += __shfl_down(a, o, 64);
  if (l == 0) rsc[row] = a + rb[0];
}

// ---------------- top-8 read indices ----------------
__global__ void topk_read(const float* __restrict__ sc, float* __restrict__ out_idx)
{
  int b = threadIdx.x; if (b >= 64) return;
  const float* p = sc + b * 128;
  unsigned long long u0 = 0, u1 = 0;
  for (int it = 0; it < 8; ++it){
    float best = -3.0e38f; int bi = 0;
    for (int j = 0; j < 128; ++j){
      bool used = (j < 64) ? ((u0 >> j) & 1) : ((u1 >> (j - 64)) & 1);
      float v = p[j];
      if (!used && v > best){ best = v; bi = j; }
    }
    if (bi < 64) u0 |= 1ull << bi; else u1 |= 1ull << (bi - 64);
    out_idx[b * 8 + it] = (float)bi;
  }
}

// ---------------- gate f32 ----------------
__global__ __launch_bounds__(256) void gate_f32(
    const float* __restrict__ aout, const float* __restrict__ gw, const float* __restrict__ gb,
    float* __restrict__ out_eidx, float* __restrict__ out_ew, float* __restrict__ gscale)
{
  int b = blockIdx.x, t = threadIdx.x;
  __shared__ float mean[512];
  __shared__ float lg[64];
  const float* ap = aout + (size_t)b * 65536;
  float s0 = 0.f, s1 = 0.f;
  for (int s = 0; s < 128; ++s){
    s0 += ap[s * 512 + t];
    s1 += ap[s * 512 + t + 256];
  }
  mean[t] = s0 * (1.f / 128.f);
  mean[t + 256] = s1 * (1.f / 128.f);
  __syncthreads();
  if (t < 64){
    float acc = gb[t];
    const float* gwr = gw + t * 512;
    for (int d = 0; d < 512; ++d) acc += mean[d] * gwr[d];
    lg[t] = acc;
  }
  __syncthreads();
  if (t == 0){
    int i0 = 0; float v0 = lg[0];
    for (int e = 1; e < 64; ++e) if (lg[e] > v0){ v0 = lg[e]; i0 = e; }
    int i1 = (i0 == 0) ? 1 : 0; float v1 = lg[i1];
    for (int e = 0; e < 64; ++e) if (e != i0 && lg[e] > v1){ v1 = lg[e]; i1 = e; }
    float e1 = expf(v1 - v0);
    float w0 = 1.f / (1.f + e1), w1 = e1 / (1.f + e1);
    out_eidx[b * 2]     = (float)i0;
    out_eidx[b * 2 + 1] = (float)i1;
    out_ew[b * 2]     = w0;
    out_ew[b * 2 + 1] = w1;
    gscale[b] = w0 + w1;
  }
}

// ---------------- slot-gate scores f32 ----------------
__global__ void slot_scores_f32(
    const float* __restrict__ eout, const float* __restrict__ sgw,
    const float* __restrict__ sgb, float* __restrict__ ssc)
{
  int row = blockIdx.x, l = threadIdx.x;
  const float* ep = eout + (size_t)row * 512;
  float a = 0.f;
  for (int d = l; d < 512; d += 64) a += ep[d] * sgw[d];
  #pragma unroll
  for (int o = 32; o; o >>= 1) a += __shfl_down(a, o, 64);
  if (l == 0) ssc[row] = a + sgb[0];
}

// ---------------- top-8 slots ----------------
__global__ void topk_slot(const float* __restrict__ sc, float* __restrict__ out_idx,
                          float* __restrict__ out_w, int* __restrict__ rowmap,
                          float* __restrict__ slotw_f)
{
  int b = threadIdx.x; if (b >= 64) return;
  const float* p = sc + b * 128;
  unsigned long long u0 = 0, u1 = 0;
  float vals[8]; int idx[8];
  for (int it = 0; it < 8; ++it){
    float best = -3.0e38f; int bi = 0;
    for (int j = 0; j < 128; ++j){
      bool used = (j < 64) ? ((u0 >> j) & 1) : ((u1 >> (j - 64)) & 1);
      float v = p[j];
      if (!used && v > best){ best = v; bi = j; }
    }
    if (bi < 64) u0 |= 1ull << bi; else u1 |= 1ull << (bi - 64);
    vals[it] = best; idx[it] = bi;
  }
  float m = vals[0], s = 0.f, e[8];
  for (int i = 0; i < 8; ++i){ e[i] = expf(vals[i] - m); s += e[i]; }
  float inv = 1.f / s;
  for (int i = 0; i < 8; ++i){
    float w = e[i] * inv;
    out_idx[b * 8 + i] = (float)idx[i];
    out_w[b * 8 + i]   = w;
    rowmap[b * 8 + i]  = b * 128 + idx[i];
    slotw_f[b * 8 + i] = w;
  }
}

// ---------------- scatter: f32 ns output + bf16 ns ----------------
__global__ __launch_bounds__(256) void finalize2_k(
    const float* __restrict__ upd, const int* __restrict__ rowmap,
    const float* __restrict__ slotw, const float* __restrict__ raw_state,
    float* __restrict__ nsf, u16* __restrict__ nsb)
{
  int m = blockIdx.x, t = threadIdx.x;
  int row = rowmap[m];
  float w = slotw[m];
  #pragma unroll
  for (int d = t; d < 512; d += 256){
    float st = raw_state[(size_t)row * 512 + d];
    float v = 0.7f * st + 0.3f * w * tanhf(upd[(size_t)m * 512 + d]);
    nsf[(size_t)row * 512 + d] = v;
    nsb[(size_t)row * 512 + d] = f2bf(v);
  }
}

// ---------------- bf16 MFMA GEMM (final output; verified) ----------------
__global__ __launch_bounds__(256) void gemm_bt(
    const u16* __restrict__ A, const u16* __restrict__ W, void* __restrict__ C,
    int M, int N, int K, int lda, int ldw, int ldc,
    long long sAo, long long sAi, int inner,
    long long sWo, long long sWi,
    long long sCo, long long sCi,
    const u16* __restrict__ bias, int bias_row,
    const float* __restrict__ rscale, int rs_shift,
    const int* __restrict__ gather,
    float oscale, int cf32, int ntiles)
{
  __shared__ __align__(16) u16 lA[128 * 32];
  __shared__ __align__(16) u16 lB[128 * 32];

  int bz = blockIdx.y;
  int oz = bz / inner, iz = bz - oz * inner;
  const u16* Ab = A + (size_t)oz * sAo + (size_t)iz * sAi;
  const u16* Wb = W + (size_t)oz * sWo + (size_t)iz * sWi;
  char* Cb = (char*)C + ((size_t)oz * sCo + (size_t)iz * sCi) * (cf32 ? 4 : 2);

  int mt = blockIdx.x / ntiles, nt = blockIdx.x - mt * ntiles;

  int tid = threadIdx.x;
  int wave = tid >> 6, lane = tid & 63;
  int wm = (wave >> 1) * 64, wn = (wave & 1) * 64;
  int fr = lane & 15, fq = lane >> 4;

  int m0  = tid >> 2, kc = tid & 3;
  int rA0 = imin(mt * 128 + m0,      M - 1);
  int rA1 = imin(mt * 128 + m0 + 64, M - 1);
  if (gather){ rA0 = gather[rA0]; rA1 = gather[rA1]; }
  int rB0 = imin(nt * 128 + m0,      N - 1);
  int rB1 = imin(nt * 128 + m0 + 64, N - 1);
  const u16* pA0 = Ab + (size_t)rA0 * lda + kc * 8;
  const u16* pA1 = Ab + (size_t)rA1 * lda + kc * 8;
  const u16* pB0 = Wb + (size_t)rB0 * ldw + kc * 8;
  const u16* pB1 = Wb + (size_t)rB1 * ldw + kc * 8;
  char* dA0 = (char*)lA + wave * 1024;
  char* dA1 = (char*)lA + 4096 + wave * 1024;
  char* dB0 = (char*)lB + wave * 1024;
  char* dB1 = (char*)lB + 4096 + wave * 1024;

  f32x4 zero = {0.f, 0.f, 0.f, 0.f};
  f32x4 acc[4][4];
  #pragma unroll
  for (int i = 0; i < 4; ++i)
    #pragma unroll
    for (int j = 0; j < 4; ++j) acc[i][j] = zero;

  for (int kt = 0; kt < K; kt += 32){
    gl_lds16(pA0 + kt, dA0);
    gl_lds16(pA1 + kt, dA1);
    gl_lds16(pB0 + kt, dB0);
    gl_lds16(pB1 + kt, dB1);
    __syncthreads();

    short8 afr[4], bfr[4];
    #pragma unroll
    for (int i = 0; i < 4; ++i){
      afr[i] = *(const short8*)&lA[(wm + i * 16 + fr) * 32 + fq * 8];
      bfr[i] = *(const short8*)&lB[(wn + i * 16 + fr) * 32 + fq * 8];
    }
    #pragma unroll
    for (int i = 0; i < 4; ++i)
      #pragma unroll
      for (int j = 0; j < 4; ++j)
        acc[i][j] = __builtin_amdgcn_mfma_f32_16x16x32_bf16(afr[i], bfr[j], acc[i][j], 0, 0, 0);
    __syncthreads();
  }

  #pragma unroll
  for (int i = 0; i < 4; ++i){
    #pragma unroll
    for (int j = 0; j < 4; ++j){
      #pragma unroll
      for (int r = 0; r < 4; ++r){
        int row = mt * 128 + wm + i * 16 + fq * 4 + r;
        int col = nt * 128 + wn + j * 16 + fr;
        if (row < M){
          float v = acc[i][j][r] * oscale;
          if (bias)   v += bf2f(bias[bias_row ? row : col]);
          if (rscale) v *= rscale[row >> rs_shift];
          size_t idx = (size_t)row * ldc + col;
          if (cf32) ((float*)Cb)[idx] = v;
          else      ((u16*)Cb)[idx]   = f2bf(v);
        }
      }
    }
  }
}

// ---------------- final out reduce ----------------
__global__ __launch_bounds__(256) void out_reduce(
    const float* __restrict__ part, const float* __restrict__ ob, float* __restrict__ out)
{
  int i = blockIdx.x * 256 + threadIdx.x;
  float a = ob[i & 511];
  for (int ks = 0; ks < 64; ++ks) a += part[(size_t)ks * 32768 + i];
  out[i] = a;
}

// ---------------- host helpers ----------------
static inline int hmin(int a, int b){ return a < b ? a : b; }

static inline void gemmF(hipStream_t st, const float* A, const float* W, float* C,
    int M, int N, int K, int lda, int ldw, int ldc,
    long long sAo, long long sAi, int inner,
    long long sWo, long long sWi, long long sCo, long long sCi, int batch,
    const float* bias, int bis, const float* rs, int rss, const int* gth, int wt)
{
  int mt = (M + 127) / 128, nt = (N + 127) / 128;
  gemm_f32<<<dim3(mt * nt, batch), dim3(256), 0, st>>>(
      A, W, C, M, N, K, lda, ldw, ldc, sAo, sAi, inner, sWo, sWi, sCo, sCi,
      bias, bis, rs, rss, gth, wt, nt);
}
static inline void gemmFb(hipStream_t st, const float* A, const float* W, float* C,
    int M, int N, int K, int lda, int ldw, int ldc,
    long long sAo, long long sAi, int inner,
    long long sWo, long long sWi, long long sCo, long long sCi, int batch,
    const float* bias, int bis, const float* rs, int rss, const int* gth, int wt)
{
  int mt = (M + 127) / 128, nt = (N + 63) / 64;
  gemm_f32b<<<dim3(mt * nt, batch), dim3(256), 0, st>>>(
      A, W, C, M, N, K, lda, ldw, ldc, sAo, sAi, inner, sWo, sWi, sCo, sCi,
      bias, bis, rs, rss, gth, wt, nt);
}
static inline void conv(hipStream_t st, const void* src, u16* dst, long long n){
  int blocks = hmin((int)((n + 255) / 256), 4096);
  conv_k<<<dim3(blocks), dim3(256), 0, st>>>((const float*)src, dst, n);
}

extern "C" void kernel_launch(void* const* d_in, const int* in_sizes, int n_in,
                              void* d_out, int out_size, void* d_ws, size_t ws_size,
                              hipStream_t stream)
{
  float* fo = (float*)d_out;

  static const int expect_sizes[22] = {
    16777216, 4194304, 262144, 512, 512, 512, 786432, 1536, 262144, 512,
    262144, 512, 32768, 64, 512, 1, 512, 1, 262144, 512, 33554432, 512 };
  bool ok = (n_in == 22);
  if (ok) for (int i = 0; i < 22; ++i) if (in_sizes[i] != expect_sizes[i]) ok = false;
  if (!ok){ fill_f32<<<dim3(128), dim3(256), 0, stream>>>(fo, 29.f * 1024.f); return; }
  if (out_size != 4228864){ fill_f32<<<dim3(128), dim3(256), 0, stream>>>(fo, 30.f * 1024.f); return; }

  const float* xR     = (const float*)d_in[0];
  const float* stateR = (const float*)d_in[1];
  const float* inwR   = (const float*)d_in[2];
  const float* inbR   = (const float*)d_in[3];
  const float* lngR   = (const float*)d_in[4];
  const float* lnbR   = (const float*)d_in[5];
  const float* ainwR  = (const float*)d_in[6];
  const float* ainbR  = (const float*)d_in[7];
  const float* aowR   = (const float*)d_in[8];
  const float* aobR   = (const float*)d_in[9];
  const float* expwR  = (const float*)d_in[10];
  const float* expbR  = (const float*)d_in[11];
  const float* gwR    = (const float*)d_in[12];
  const float* gbR    = (const float*)d_in[13];
  const float* rwR    = (const float*)d_in[14];
  const float* rbR    = (const float*)d_in[15];
  const float* sgwR   = (const float*)d_in[16];
  const float* sgbR   = (const float*)d_in[17];
  const float* stwR   = (const float*)d_in[18];
  const float* stbR   = (const float*)d_in[19];
  const float* outwR  = (const float*)d_in[20];
  const float* outbR  = (const float*)d_in[21];

  float* outp  = fo;
  float* nsf   = fo + 32768;
  float* sidx  = fo + 4227072;
  float* ridx  = fo + 4227584;
  float* eidx  = fo + 4228096;
  float* swout = fo + 4228224;
  float* ewout = fo + 4228736;

  char* wsp = (char*)d_ws;
  size_t o = 0;
  auto alloc = [&](size_t bytes){ size_t r = o; o += (bytes + 255) & ~(size_t)255; return r; };
  float* kvf    = (float*)(wsp + alloc(83886080));
  float* qf     = (float*)(wsp + alloc(16777216));
  float* qkpv   = (float*)(wsp + alloc(16777216));
  float* scoresb= (float*)(wsp + alloc(20971520));
  float* attnf  = (float*)(wsp + alloc(16777216));
  float* opart  = (float*)(wsp + alloc(8388608));
  float* updf   = (float*)(wsp + alloc(1048576));
  float* ainwT  = (float*)(wsp + alloc(1048576));
  float* rsc    = (float*)(wsp + alloc(32768));
  float* ssc    = (float*)(wsp + alloc(32768));
  float* gscale = (float*)(wsp + alloc(256));
  int*   rowmap = (int*)  (wsp + alloc(2048));
  float* slotw  = (float*)(wsp + alloc(2048));
  u16* nsb      = (u16*)  (wsp + alloc(8388608));

  u16*   out_w_c = (u16*)kvf;
  float* aoutf   = qf;
  float* eoutf   = attnf;

  if (ws_size < o){ fill_f32<<<dim3(128), dim3(256), 0, stream>>>(fo, 31.f * 1024.f); return; }

  transp_f32<<<dim3(64), dim3(256), 0, stream>>>(ainwR, ainwT);
  conv(stream, stateR, nsb, 4194304);

  // 1) LayerNorm -> kvf slots ; read-gate
  ln_f32<<<dim3(8192), dim3(256), 0, stream>>>(stateR, lngR, lnbR, kvf);
  rscore_k<<<dim3(8192), dim3(64), 0, stream>>>(stateR, rwR, rbR, rsc);
  topk_read<<<dim3(1), dim3(64), 0, stream>>>(rsc, ridx);
  // 2) x_proj -> kvf rows 0..511
  gemmF(stream, xR, inwR, kvf, 512, 512, 512, 512, 512, 512,
        262144, 0, 1, 0, 0, 327680, 0, 64, inbR, 0, nullptr, 0, nullptr, 1);
  // 3) q -> qf
  gemmFb(stream, kvf + 262144, ainwR, qf, 128, 512, 512, 512, 512, 512,
        327680, 0, 1, 0, 0, 65536, 0, 64, ainbR, 0, nullptr, 0, nullptr, 1);
  // 4) attention (GEMM factorization), chunks of 16 batches
  for (int cb = 0; cb < 4; ++cb){
    const float* qc  = qf  + (size_t)cb * 16 * 65536;
    const float* kvc = kvf + (size_t)cb * 16 * 327680;
    float* atc = attnf + (size_t)cb * 16 * 65536;
    gemmFb(stream, qc, ainwT, qkpv, 128, 512, 128, 512, 512, 512,
          65536, 128, 4, 0, 128, 262144, 65536, 64,
          nullptr, 0, nullptr, 0, nullptr, 1);
    gemmFb(stream, qkpv, kvc, scoresb, 128, 640, 512, 512, 512, 640,
          262144, 65536, 4, 327680, 0, 327680, 81920, 64,
          nullptr, 0, nullptr, 0, nullptr, 1);
    softmax_f32<<<dim3(8192), dim3(256), 0, stream>>>(scoresb, 0.08838834764831845f);
    gemmFb(stream, scoresb, kvc, qkpv, 128, 512, 640, 640, 512, 512,
          327680, 81920, 4, 327680, 0, 262144, 65536, 64,
          nullptr, 0, nullptr, 0, nullptr, 0);
    gemmFb(stream, qkpv, ainwR + (size_t)1024 * 512, atc, 128, 128, 512, 512, 512, 512,
          262144, 65536, 4, 0, 65536, 65536, 128, 64,
          ainbR + 1024, 128, nullptr, 0, nullptr, 1);
  }
  // 5) attn_out
  gemmF(stream, attnf, aowR, aoutf, 8192, 512, 512, 512, 512, 512,
        0, 0, 1, 0, 0, 0, 0, 1, aobR, 0, nullptr, 0, nullptr, 1);
  // 6) gate
  gate_f32<<<dim3(64), dim3(256), 0, stream>>>(aoutf, gwR, gbR, eidx, ewout, gscale);
  // 7) expert_out
  gemmF(stream, aoutf, expwR, eoutf, 8192, 512, 512, 512, 512, 512,
        0, 0, 1, 0, 0, 0, 0, 1, expbR, 0, gscale, 7, nullptr, 1);
  // 8) slot scores + top-8
  slot_scores_f32<<<dim3(8192), dim3(64), 0, stream>>>(eoutf, sgwR, sgbR, ssc);
  topk_slot<<<dim3(1), dim3(64), 0, stream>>>(ssc, sidx, swout, rowmap, slotw);
  // 9) upd
  gemmFb(stream, eoutf, stwR, updf, 512, 512, 512, 512, 512, 512,
        0, 0, 1, 0, 0, 0, 0, 1, stbR, 0, nullptr, 0, rowmap, 1);
  // 10) next_state
  copyf32_k<<<dim3(4096), dim3(256), 0, stream>>>((const uint4*)stateR, (uint4*)nsf);
  finalize2_k<<<dim3(512), dim3(256), 0, stream>>>(updf, rowmap, slotw, stateR, nsf, nsb);
  // 11) out_w -> bf16 (overlays kvf)
  conv(stream, outwR, out_w_c, 33554432);
  // 12) final output GEMM (bf16 MFMA) + reduce
  gemm_bt<<<dim3(4, 64), dim3(256), 0, stream>>>(
      nsb, out_w_c, opart, 64, 512, 1024, 65536, 65536, 512,
      1024, 0, 1, 1024, 0, 32768, 0,
      nullptr, 0, nullptr, 0, nullptr, 1.f, 1, 4);
  out_reduce<<<dim3(128), dim3(256), 0, stream>>>(opart, outbR, outp);
}